// Round 1
// baseline (8772.366 us; speedup 1.0000x reference)
//
#include <hip/hip_runtime.h>
#include <stdint.h>

#define DB   8
#define DC   64
#define DLX  256
#define DLY  256
#define DD   768
#define DH0  1536
#define DH1  768
#define NBC  (DB*DC)        // 512
#define NTOK (NBC*DLX)      // 131072

__device__ __forceinline__ float softplusf(float x){
  return fmaxf(x, 0.0f) + log1pf(expf(-fabsf(x)));
}

__device__ __forceinline__ unsigned long long packkey(float s, unsigned y){
  unsigned u = __float_as_uint(s);
  u = (u & 0x80000000u) ? ~u : (u | 0x80000000u);   // order-preserving map
  return ((unsigned long long)u << 32) | (unsigned long long)(0xFFFFFFFFu - y);
}

__device__ __forceinline__ unsigned long long ullmax2(unsigned long long a, unsigned long long b){
  return a > b ? a : b;
}

// ---------------- weight transposes ----------------
// W0 [1536 out][1536 in] -> W0xT [768 in][1536 out] (in<768), W0yT [768][1536] (in>=768)
__global__ __launch_bounds__(256) void k_tw0(const float* __restrict__ W0,
                                             float* __restrict__ W0xT,
                                             float* __restrict__ W0yT){
  __shared__ float t[32][33];
  int i0 = blockIdx.x * 32, o0 = blockIdx.y * 32;
  int tx = threadIdx.x & 31, ty = threadIdx.x >> 5;
  #pragma unroll
  for (int k = 0; k < 4; k++){
    int r = ty + k * 8;
    t[r][tx] = W0[(size_t)(o0 + r) * DH0 + i0 + tx];
  }
  __syncthreads();
  #pragma unroll
  for (int k = 0; k < 4; k++){
    int r = ty + k * 8;
    float v = t[tx][r];            // = W0[o0+tx][i0+r]
    int i = i0 + r;
    if (i < DD) W0xT[(size_t)i * DH0 + o0 + tx] = v;
    else        W0yT[(size_t)(i - DD) * DH0 + o0 + tx] = v;
  }
}

// W1 [768 out][1536 in] -> W1T [1536][768]
__global__ __launch_bounds__(256) void k_tw1(const float* __restrict__ W1,
                                             float* __restrict__ W1T){
  __shared__ float t[32][33];
  int i0 = blockIdx.x * 32, p0 = blockIdx.y * 32;
  int tx = threadIdx.x & 31, ty = threadIdx.x >> 5;
  #pragma unroll
  for (int k = 0; k < 4; k++){
    int r = ty + k * 8;
    t[r][tx] = W1[(size_t)(p0 + r) * DH0 + i0 + tx];
  }
  __syncthreads();
  #pragma unroll
  for (int k = 0; k < 4; k++){
    int r = ty + k * 8;
    W1T[(size_t)(i0 + r) * DH1 + p0 + tx] = t[tx][r];
  }
}

// ---------------- scores + argmax ----------------
// grid (16, 512): 4x4 tiles of 64x64 over scores[256x,256y] per (b,c)
__global__ __launch_bounds__(256) void k_scores(const float* __restrict__ xs,
                                                const float* __restrict__ ys,
                                                unsigned long long* __restrict__ amax){
  int bc = blockIdx.y;
  int b  = bc >> 6;
  int x0 = (blockIdx.x >> 2) * 64, y0 = (blockIdx.x & 3) * 64;
  const float* X = xs + (size_t)b  * DLX * DD;
  const float* Y = ys + (size_t)bc * DLY * DD;
  __shared__ float At[16][68];
  __shared__ float Bt[16][68];
  __shared__ unsigned long long cand[64][16];
  int tid = threadIdx.x;
  int xg = tid >> 4, yg = tid & 15;
  int lr = tid >> 2, lc = (tid & 3) * 4;
  float acc[4][4] = {};
  const float* arow = X + (size_t)(x0 + lr) * DD;
  const float* brow = Y + (size_t)(y0 + lr) * DD;
  for (int k0 = 0; k0 < DD; k0 += 16){
    float4 a  = *(const float4*)(arow + k0 + lc);
    float4 bv = *(const float4*)(brow + k0 + lc);
    __syncthreads();
    At[lc+0][lr]=a.x;  At[lc+1][lr]=a.y;  At[lc+2][lr]=a.z;  At[lc+3][lr]=a.w;
    Bt[lc+0][lr]=bv.x; Bt[lc+1][lr]=bv.y; Bt[lc+2][lr]=bv.z; Bt[lc+3][lr]=bv.w;
    __syncthreads();
    #pragma unroll
    for (int kk = 0; kk < 16; kk++){
      float a_[4], b_[4];
      *(float4*)a_ = *(const float4*)&At[kk][xg*4];
      *(float4*)b_ = *(const float4*)&Bt[kk][yg*4];
      #pragma unroll
      for (int i = 0; i < 4; i++)
        #pragma unroll
        for (int j = 0; j < 4; j++)
          acc[i][j] += a_[i] * b_[j];
    }
  }
  #pragma unroll
  for (int i = 0; i < 4; i++){
    unsigned long long best = 0ull;
    #pragma unroll
    for (int j = 0; j < 4; j++)
      best = ullmax2(best, packkey(acc[i][j], (unsigned)(y0 + yg*4 + j)));
    cand[xg*4 + i][yg] = best;
  }
  __syncthreads();
  if (tid < 64){
    unsigned long long m = cand[tid][0];
    #pragma unroll
    for (int j = 1; j < 16; j++) m = ullmax2(m, cand[tid][j]);
    atomicMax(&amax[(size_t)bc * DLX + x0 + tid], m);
  }
}

// ---------------- generic 128x128x16 fp32 GEMM ----------------
// MODE 0: X0 = xs @ W0xT + b0                     (A contiguous, K=768,  N=1536)
// MODE 1: h0 = softplus(ysel @ W0yT + X0_gather)  (A gathered,   K=768,  N=1536)
// MODE 2: spart = (softplus(h0 @ W1T + b1)) . w2  (A contiguous, K=1536, N=768)
template<int MODE>
__global__ __launch_bounds__(256) void k_gemm(const float* __restrict__ A,
                                              const float* __restrict__ Bt,
                                              const float* __restrict__ bias,
                                              const float* __restrict__ X0,
                                              const unsigned long long* __restrict__ amax,
                                              const float* __restrict__ w2,
                                              float* __restrict__ Cout,
                                              int bc0){
  constexpr int K = (MODE == 2) ? DH0 : DD;
  constexpr int N = (MODE == 2) ? DH1 : DH0;
  const int rt0 = blockIdx.x * 128;
  const int n0  = blockIdx.y * 128;
  const int tid = threadIdx.x;
  __shared__ float Atl[16][132];
  __shared__ float Btl[16][132];
  __shared__ int yidx[128];

  const int sr = tid >> 1, sc = (tid & 1) * 8;     // A staging
  const int br = tid >> 4, bcl = (tid & 15) * 8;   // B staging
  const int trow = tid >> 4, tcol = tid & 15;      // compute mapping

  int bc = 0;
  const float* arow;
  if constexpr (MODE == 1){
    bc = bc0 + (rt0 >> 8);
    if (tid < 128){
      unsigned long long v = amax[(size_t)bc * DLX + (rt0 & 255) + tid];
      yidx[tid] = (int)(0xFFFFFFFFu - (unsigned)(v & 0xFFFFFFFFu));
    }
    __syncthreads();
    arow = A + ((size_t)bc * DLY + (size_t)yidx[sr]) * DD;
  } else if constexpr (MODE == 0){
    arow = A + (size_t)(rt0 + sr) * DD;
  } else {
    arow = A + (size_t)(rt0 + sr) * DH0;
  }
  const float* bbase = Bt + (size_t)br * N + n0 + bcl;

  float acc[8][8] = {};
  for (int k0 = 0; k0 < K; k0 += 16){
    float4 a0  = *(const float4*)(arow + k0 + sc);
    float4 a1  = *(const float4*)(arow + k0 + sc + 4);
    float4 bv0 = *(const float4*)(bbase + (size_t)k0 * N);
    float4 bv1 = *(const float4*)(bbase + (size_t)k0 * N + 4);
    __syncthreads();
    Atl[sc+0][sr]=a0.x; Atl[sc+1][sr]=a0.y; Atl[sc+2][sr]=a0.z; Atl[sc+3][sr]=a0.w;
    Atl[sc+4][sr]=a1.x; Atl[sc+5][sr]=a1.y; Atl[sc+6][sr]=a1.z; Atl[sc+7][sr]=a1.w;
    *(float4*)&Btl[br][bcl]     = bv0;
    *(float4*)&Btl[br][bcl + 4] = bv1;
    __syncthreads();
    #pragma unroll
    for (int kk = 0; kk < 16; kk++){
      float a_[8], b_[8];
      *(float4*)&a_[0] = *(const float4*)&Atl[kk][trow*8];
      *(float4*)&a_[4] = *(const float4*)&Atl[kk][trow*8 + 4];
      *(float4*)&b_[0] = *(const float4*)&Btl[kk][tcol*8];
      *(float4*)&b_[4] = *(const float4*)&Btl[kk][tcol*8 + 4];
      #pragma unroll
      for (int i = 0; i < 8; i++)
        #pragma unroll
        for (int j = 0; j < 8; j++)
          acc[i][j] += a_[i] * b_[j];
    }
  }

  if constexpr (MODE == 0){
    float bl[8];
    #pragma unroll
    for (int j = 0; j < 8; j++) bl[j] = bias[n0 + tcol*8 + j];
    #pragma unroll
    for (int i = 0; i < 8; i++){
      int row = rt0 + trow*8 + i;
      float v[8];
      #pragma unroll
      for (int j = 0; j < 8; j++) v[j] = acc[i][j] + bl[j];
      *(float4*)(Cout + (size_t)row * N + n0 + tcol*8)     = *(float4*)&v[0];
      *(float4*)(Cout + (size_t)row * N + n0 + tcol*8 + 4) = *(float4*)&v[4];
    }
  } else if constexpr (MODE == 1){
    #pragma unroll
    for (int i = 0; i < 8; i++){
      int r = rt0 + trow*8 + i;                       // chunk-local row
      size_t xrow = (size_t)(bc >> 6) * DLX + (r & 255);
      const float* x0p = X0 + xrow * DH0 + n0 + tcol*8;
      float v[8];
      #pragma unroll
      for (int j = 0; j < 8; j++) v[j] = softplusf(acc[i][j] + x0p[j]);
      *(float4*)(Cout + (size_t)r * DH0 + n0 + tcol*8)     = *(float4*)&v[0];
      *(float4*)(Cout + (size_t)r * DH0 + n0 + tcol*8 + 4) = *(float4*)&v[4];
    }
  } else {
    float bl[8], wl[8];
    #pragma unroll
    for (int j = 0; j < 8; j++){ bl[j] = bias[n0 + tcol*8 + j]; wl[j] = w2[n0 + tcol*8 + j]; }
    #pragma unroll
    for (int i = 0; i < 8; i++){
      float p = 0.0f;
      #pragma unroll
      for (int j = 0; j < 8; j++) p += softplusf(acc[i][j] + bl[j]) * wl[j];
      #pragma unroll
      for (int m = 1; m < 16; m <<= 1) p += __shfl_xor(p, m, 64);
      if (tcol == 0){
        size_t token = (size_t)bc0 * DLX + rt0 + trow*8 + i;
        Cout[token * 6 + blockIdx.y] = p;
      }
    }
  }
}

// ---------------- final reduce: out[b,c] = sum_x sum_nb spart + 256*b2 ----------------
__global__ __launch_bounds__(256) void k_reduce(const float* __restrict__ spart,
                                                const float* __restrict__ b2,
                                                float* __restrict__ out){
  int bc = blockIdx.x, tid = threadIdx.x;
  const float* p = spart + ((size_t)bc * DLX + tid) * 6;
  float s = 0.0f;
  #pragma unroll
  for (int j = 0; j < 6; j++) s += p[j];
  __shared__ float red[256];
  red[tid] = s;
  __syncthreads();
  for (int off = 128; off > 0; off >>= 1){
    if (tid < off) red[tid] += red[tid + off];
    __syncthreads();
  }
  if (tid == 0) out[bc] = red[0] + 256.0f * b2[0];
}

extern "C" void kernel_launch(void* const* d_in, const int* in_sizes, int n_in,
                              void* d_out, int out_size, void* d_ws, size_t ws_size,
                              hipStream_t stream){
  const float* xs = (const float*)d_in[0];
  const float* ys = (const float*)d_in[1];
  const float* W0 = (const float*)d_in[2];
  const float* b0 = (const float*)d_in[3];
  const float* W1 = (const float*)d_in[4];
  const float* b1 = (const float*)d_in[5];
  const float* W2 = (const float*)d_in[6];
  const float* b2 = (const float*)d_in[7];
  float* out = (float*)d_out;

  char* w = (char*)d_ws;
  size_t off = 0;
  auto alloc = [&](size_t bytes)->void*{
    void* p = w + off;
    off += (bytes + 255) & ~(size_t)255;
    return p;
  };
  unsigned long long* amax = (unsigned long long*)alloc((size_t)NTOK * 8);
  float* X0   = (float*)alloc((size_t)DB * DLX * DH0 * 4);
  float* W0xT = (float*)alloc((size_t)DD * DH0 * 4);
  float* W0yT = (float*)alloc((size_t)DD * DH0 * 4);
  float* W1T  = (float*)alloc((size_t)DH0 * DH1 * 4);
  float* spart= (float*)alloc((size_t)NTOK * 6 * 4);
  size_t fixed = off;
  size_t per_bc = (size_t)DLX * DH0 * 4;           // 1.57 MB / (b,c)
  int G = 1;
  if (ws_size > fixed){
    long long g = (long long)((ws_size - fixed) / per_bc);
    G = (int)(g < 1 ? 1 : (g > 64 ? 64 : g));
  }
  float* h0c = (float*)alloc(per_bc * (size_t)G);

  hipMemsetAsync(amax, 0, (size_t)NTOK * 8, stream);
  k_tw0<<<dim3(48, 48), 256, 0, stream>>>(W0, W0xT, W0yT);
  k_tw1<<<dim3(48, 24), 256, 0, stream>>>(W1, W1T);
  k_scores<<<dim3(16, NBC), 256, 0, stream>>>(xs, ys, amax);
  k_gemm<0><<<dim3(16, 12), 256, 0, stream>>>(xs, W0xT, b0, nullptr, nullptr, nullptr, X0, 0);
  for (int bc0 = 0; bc0 < NBC; bc0 += G){
    int g = (NBC - bc0) < G ? (NBC - bc0) : G;
    k_gemm<1><<<dim3(2*g, 12), 256, 0, stream>>>(ys, W0yT, nullptr, X0, amax, nullptr, h0c, bc0);
    k_gemm<2><<<dim3(2*g, 6), 256, 0, stream>>>(h0c, W1T, b1, nullptr, nullptr, W2, spart, bc0);
  }
  k_reduce<<<NBC, 256, 0, stream>>>(spart, b2, out);
}

// Round 2
// 3880.718 us; speedup vs baseline: 2.2605x; 2.2605x over previous
//
#include <hip/hip_runtime.h>
#include <stdint.h>

#define DB   8
#define DC   64
#define DLX  256
#define DLY  256
#define DD   768
#define DH0  1536
#define DH1  768
#define NBC  (DB*DC)        // 512
#define NTOK (NBC*DLX)      // 131072

typedef float f32x4 __attribute__((ext_vector_type(4)));
typedef __bf16 bf16x8 __attribute__((ext_vector_type(8)));

__device__ __forceinline__ float softplusf(float x){
  return fmaxf(x, 0.0f) + log1pf(expf(-fabsf(x)));
}

__device__ __forceinline__ unsigned short f2bf(float f){
  unsigned u = __float_as_uint(f);
  unsigned r = (u + 0x7FFFu + ((u >> 16) & 1u)) >> 16;
  return (unsigned short)r;
}
__device__ __forceinline__ float bf2f(unsigned short h){
  return __uint_as_float((unsigned)h << 16);
}

__device__ __forceinline__ unsigned long long packkey(float s, unsigned y){
  unsigned u = __float_as_uint(s);
  u = (u & 0x80000000u) ? ~u : (u | 0x80000000u);   // order-preserving map
  return ((unsigned long long)u << 32) | (unsigned long long)(0xFFFFFFFFu - y);
}
__device__ __forceinline__ unsigned long long ullmax2(unsigned long long a, unsigned long long b){
  return a > b ? a : b;
}

// async global->LDS, 16B per lane; lds base must be wave-uniform
__device__ __forceinline__ void gload_lds16(const void* g, void* l){
  __builtin_amdgcn_global_load_lds((const __attribute__((address_space(1))) void*)g,
                                   (__attribute__((address_space(3))) void*)l,
                                   16, 0, 0);
}

// stage a [128 rows][32 k] bf16 tile from row-major matrix M (row stride ld elems)
__device__ __forceinline__ void stage_tile(const unsigned short* __restrict__ M, int ld,
                                           int row0, int k0, unsigned short* lds,
                                           int l, int w){
  #pragma unroll
  for (int i = 0; i < 2; i++){
    int blk = w*2 + i;                   // 0..7, 16 rows each
    int row = blk*16 + (l >> 2);
    int kg  = (l & 3) * 8;
    gload_lds16(M + (size_t)(row0 + row)*ld + k0 + kg, lds + blk*512);
  }
}

// ---------------- W0xT transpose (fp32, for X0 GEMM) ----------------
__global__ __launch_bounds__(256) void k_tw0(const float* __restrict__ W0,
                                             float* __restrict__ W0xT){
  __shared__ float t[32][33];
  int i0 = blockIdx.x * 32, o0 = blockIdx.y * 32;
  int tx = threadIdx.x & 31, ty = threadIdx.x >> 5;
  #pragma unroll
  for (int k = 0; k < 4; k++){
    int r = ty + k * 8;
    t[r][tx] = W0[(size_t)(o0 + r) * DH0 + i0 + tx];
  }
  __syncthreads();
  #pragma unroll
  for (int k = 0; k < 4; k++){
    int r = ty + k * 8;
    W0xT[(size_t)(i0 + r) * DH0 + o0 + tx] = t[tx][r];
  }
}

// ---------------- split fp32 matrix into bf16 hi/lo planes ----------------
// reads src[r*ld + off + c], writes hi/lo[r*cols + c], c in [0,cols)
__global__ __launch_bounds__(256) void k_split(const float* __restrict__ src, int ld, int off,
                                               int rows, int cols,
                                               unsigned short* __restrict__ hi,
                                               unsigned short* __restrict__ lo){
  int total = rows * (cols >> 2);
  for (int idx = blockIdx.x * 256 + threadIdx.x; idx < total; idx += gridDim.x * 256){
    int r = idx / (cols >> 2), c4 = (idx % (cols >> 2)) * 4;
    float4 f = *(const float4*)(src + (size_t)r * ld + off + c4);
    unsigned short h0 = f2bf(f.x), h1 = f2bf(f.y), h2 = f2bf(f.z), h3 = f2bf(f.w);
    ushort4 hv, lv;
    hv.x = h0; hv.y = h1; hv.z = h2; hv.w = h3;
    lv.x = f2bf(f.x - bf2f(h0)); lv.y = f2bf(f.y - bf2f(h1));
    lv.z = f2bf(f.z - bf2f(h2)); lv.w = f2bf(f.w - bf2f(h3));
    *(ushort4*)(hi + (size_t)r * cols + c4) = hv;
    *(ushort4*)(lo + (size_t)r * cols + c4) = lv;
  }
}

// ---------------- scores + argmax (fp32, unchanged) ----------------
__global__ __launch_bounds__(256) void k_scores(const float* __restrict__ xs,
                                                const float* __restrict__ ys,
                                                unsigned long long* __restrict__ amax){
  int bc = blockIdx.y;
  int b  = bc >> 6;
  int x0 = (blockIdx.x >> 2) * 64, y0 = (blockIdx.x & 3) * 64;
  const float* X = xs + (size_t)b  * DLX * DD;
  const float* Y = ys + (size_t)bc * DLY * DD;
  __shared__ float At[16][68];
  __shared__ float Bt[16][68];
  __shared__ unsigned long long cand[64][16];
  int tid = threadIdx.x;
  int xg = tid >> 4, yg = tid & 15;
  int lr = tid >> 2, lc = (tid & 3) * 4;
  float acc[4][4] = {};
  const float* arow = X + (size_t)(x0 + lr) * DD;
  const float* brow = Y + (size_t)(y0 + lr) * DD;
  for (int k0 = 0; k0 < DD; k0 += 16){
    float4 a  = *(const float4*)(arow + k0 + lc);
    float4 bv = *(const float4*)(brow + k0 + lc);
    __syncthreads();
    At[lc+0][lr]=a.x;  At[lc+1][lr]=a.y;  At[lc+2][lr]=a.z;  At[lc+3][lr]=a.w;
    Bt[lc+0][lr]=bv.x; Bt[lc+1][lr]=bv.y; Bt[lc+2][lr]=bv.z; Bt[lc+3][lr]=bv.w;
    __syncthreads();
    #pragma unroll
    for (int kk = 0; kk < 16; kk++){
      float a_[4], b_[4];
      *(float4*)a_ = *(const float4*)&At[kk][xg*4];
      *(float4*)b_ = *(const float4*)&Bt[kk][yg*4];
      #pragma unroll
      for (int i = 0; i < 4; i++)
        #pragma unroll
        for (int j = 0; j < 4; j++)
          acc[i][j] += a_[i] * b_[j];
    }
  }
  #pragma unroll
  for (int i = 0; i < 4; i++){
    unsigned long long best = 0ull;
    #pragma unroll
    for (int j = 0; j < 4; j++)
      best = ullmax2(best, packkey(acc[i][j], (unsigned)(y0 + yg*4 + j)));
    cand[xg*4 + i][yg] = best;
  }
  __syncthreads();
  if (tid < 64){
    unsigned long long m = cand[tid][0];
    #pragma unroll
    for (int j = 1; j < 16; j++) m = ullmax2(m, cand[tid][j]);
    atomicMax(&amax[(size_t)bc * DLX + x0 + tid], m);
  }
}

// ---------------- X0 = xs @ W0xT + b0 (fp32 vector GEMM, K=768, N=1536) ----------------
__global__ __launch_bounds__(256) void k_x0(const float* __restrict__ A,
                                            const float* __restrict__ Bt,
                                            const float* __restrict__ bias,
                                            float* __restrict__ Cout){
  const int rt0 = blockIdx.x * 128;
  const int n0  = blockIdx.y * 128;
  const int tid = threadIdx.x;
  __shared__ float Atl[16][132];
  __shared__ float Btl[16][132];
  const int sr = tid >> 1, sc = (tid & 1) * 8;
  const int br = tid >> 4, bcl = (tid & 15) * 8;
  const int trow = tid >> 4, tcol = tid & 15;
  const float* arow  = A + (size_t)(rt0 + sr) * DD;
  const float* bbase = Bt + (size_t)br * DH0 + n0 + bcl;
  float acc[8][8] = {};
  for (int k0 = 0; k0 < DD; k0 += 16){
    float4 a0  = *(const float4*)(arow + k0 + sc);
    float4 a1  = *(const float4*)(arow + k0 + sc + 4);
    float4 bv0 = *(const float4*)(bbase + (size_t)k0 * DH0);
    float4 bv1 = *(const float4*)(bbase + (size_t)k0 * DH0 + 4);
    __syncthreads();
    Atl[sc+0][sr]=a0.x; Atl[sc+1][sr]=a0.y; Atl[sc+2][sr]=a0.z; Atl[sc+3][sr]=a0.w;
    Atl[sc+4][sr]=a1.x; Atl[sc+5][sr]=a1.y; Atl[sc+6][sr]=a1.z; Atl[sc+7][sr]=a1.w;
    *(float4*)&Btl[br][bcl]     = bv0;
    *(float4*)&Btl[br][bcl + 4] = bv1;
    __syncthreads();
    #pragma unroll
    for (int kk = 0; kk < 16; kk++){
      float a_[8], b_[8];
      *(float4*)&a_[0] = *(const float4*)&Atl[kk][trow*8];
      *(float4*)&a_[4] = *(const float4*)&Atl[kk][trow*8 + 4];
      *(float4*)&b_[0] = *(const float4*)&Btl[kk][tcol*8];
      *(float4*)&b_[4] = *(const float4*)&Btl[kk][tcol*8 + 4];
      #pragma unroll
      for (int i = 0; i < 8; i++)
        #pragma unroll
        for (int j = 0; j < 8; j++)
          acc[i][j] += a_[i] * b_[j];
    }
  }
  float bl[8];
  #pragma unroll
  for (int j = 0; j < 8; j++) bl[j] = bias[n0 + tcol*8 + j];
  #pragma unroll
  for (int i = 0; i < 8; i++){
    int row = rt0 + trow*8 + i;
    float v[8];
    #pragma unroll
    for (int j = 0; j < 8; j++) v[j] = acc[i][j] + bl[j];
    *(float4*)(Cout + (size_t)row * DH0 + n0 + tcol*8)     = *(float4*)&v[0];
    *(float4*)(Cout + (size_t)row * DH0 + n0 + tcol*8 + 4) = *(float4*)&v[4];
  }
}

// ---------------- layer0 MFMA: h0 = softplus(ysel @ W0y^T + X0) ----------------
// tile 128(tokens) x 128(n), K=768, split-bf16 (3 MFMA passes)
__global__ __launch_bounds__(256, 2) void k_l0(const float* __restrict__ ys,
        const unsigned long long* __restrict__ amax,
        const unsigned short* __restrict__ W0yh, const unsigned short* __restrict__ W0yl,
        const float* __restrict__ X0,
        unsigned short* __restrict__ H0h, unsigned short* __restrict__ H0l,
        int bc0){
  __shared__ __align__(16) unsigned short Ah[128*32], Al[128*32], Bh[128*32], Bl[128*32];
  __shared__ int yidx[128];
  const int tid = threadIdx.x;
  const int rt0 = blockIdx.x * 128;           // chunk-local token base
  const int n0  = blockIdx.y * 128;
  const int bc  = bc0 + (blockIdx.x >> 1);
  const int b   = bc >> 6;
  const int xbase = rt0 & 255;

  if (tid < 128){
    unsigned long long v = amax[(size_t)bc * DLX + xbase + tid];
    yidx[tid] = (int)(0xFFFFFFFFu - (unsigned)(v & 0xFFFFFFFFu));
  }
  __syncthreads();

  const int l = tid & 63, w = tid >> 6;
  const int wr = w >> 1, wc = w & 1;
  const int lrow = l & 15, kb = l >> 4;
  const int aoff = (wr*64 + lrow)*32 + kb*8;
  const int boff = (wc*64 + lrow)*32 + kb*8;

  const int sr = tid >> 1, sc0 = (tid & 1) * 16;
  const float* asrc = ys + ((size_t)bc * DLY + (size_t)yidx[sr]) * DD + sc0;

  f32x4 acc[4][4];
  #pragma unroll
  for (int i = 0; i < 4; i++)
    #pragma unroll
    for (int j = 0; j < 4; j++) acc[i][j] = (f32x4){0.f,0.f,0.f,0.f};

  for (int k0 = 0; k0 < DD; k0 += 32){
    float f[16];
    *(float4*)&f[0]  = *(const float4*)(asrc + k0);
    *(float4*)&f[4]  = *(const float4*)(asrc + k0 + 4);
    *(float4*)&f[8]  = *(const float4*)(asrc + k0 + 8);
    *(float4*)&f[12] = *(const float4*)(asrc + k0 + 12);
    unsigned __attribute__((aligned(16))) hw[8], lw[8];
    #pragma unroll
    for (int j = 0; j < 8; j++){
      unsigned short h0 = f2bf(f[2*j]), h1 = f2bf(f[2*j+1]);
      unsigned short l0 = f2bf(f[2*j] - bf2f(h0)), l1 = f2bf(f[2*j+1] - bf2f(h1));
      hw[j] = (unsigned)h0 | ((unsigned)h1 << 16);
      lw[j] = (unsigned)l0 | ((unsigned)l1 << 16);
    }
    __syncthreads();
    *(uint4*)&Ah[sr*32 + sc0]     = *(uint4*)&hw[0];
    *(uint4*)&Ah[sr*32 + sc0 + 8] = *(uint4*)&hw[4];
    *(uint4*)&Al[sr*32 + sc0]     = *(uint4*)&lw[0];
    *(uint4*)&Al[sr*32 + sc0 + 8] = *(uint4*)&lw[4];
    stage_tile(W0yh, DD, n0, k0, Bh, l, w);
    stage_tile(W0yl, DD, n0, k0, Bl, l, w);
    __syncthreads();
    bf16x8 a_h[4], a_l[4], b_h[4], b_l[4];
    #pragma unroll
    for (int i = 0; i < 4; i++){
      a_h[i] = *(const bf16x8*)&Ah[aoff + i*512];
      a_l[i] = *(const bf16x8*)&Al[aoff + i*512];
      b_h[i] = *(const bf16x8*)&Bh[boff + i*512];
      b_l[i] = *(const bf16x8*)&Bl[boff + i*512];
    }
    #pragma unroll
    for (int i = 0; i < 4; i++)
      #pragma unroll
      for (int j = 0; j < 4; j++){
        acc[i][j] = __builtin_amdgcn_mfma_f32_16x16x32_bf16(a_h[i], b_h[j], acc[i][j], 0, 0, 0);
        acc[i][j] = __builtin_amdgcn_mfma_f32_16x16x32_bf16(a_l[i], b_h[j], acc[i][j], 0, 0, 0);
        acc[i][j] = __builtin_amdgcn_mfma_f32_16x16x32_bf16(a_h[i], b_l[j], acc[i][j], 0, 0, 0);
      }
  }

  #pragma unroll
  for (int mi = 0; mi < 4; mi++)
    #pragma unroll
    for (int ni = 0; ni < 4; ni++){
      int n = n0 + wc*64 + ni*16 + lrow;
      #pragma unroll
      for (int r = 0; r < 4; r++){
        int m = wr*64 + mi*16 + kb*4 + r;
        int t = rt0 + m;
        float x0v = X0[((size_t)b * DLX + (unsigned)(xbase + m)) * DH0 + n];
        float v = softplusf(acc[mi][ni][r] + x0v);
        unsigned short h = f2bf(v);
        H0h[(size_t)t * DH0 + n] = h;
        H0l[(size_t)t * DH0 + n] = f2bf(v - bf2f(h));
      }
    }
}

// ---------------- layer1+2 MFMA: spart = softplus(h0 @ W1^T + b1) . w2 ----------------
// tile 128(tokens) x 128(n of 768), K=1536, split-bf16
__global__ __launch_bounds__(256, 2) void k_l1(const unsigned short* __restrict__ H0h,
        const unsigned short* __restrict__ H0l,
        const unsigned short* __restrict__ W1h, const unsigned short* __restrict__ W1l,
        const float* __restrict__ b1, const float* __restrict__ w2,
        float* __restrict__ spart, int bc0){
  __shared__ __align__(16) unsigned short Ah[128*32], Al[128*32], Bh[128*32], Bl[128*32];
  const int tid = threadIdx.x;
  const int rt0 = blockIdx.x * 128;
  const int n0  = blockIdx.y * 128;
  const int l = tid & 63, w = tid >> 6;
  const int wr = w >> 1, wc = w & 1;
  const int lrow = l & 15, kb = l >> 4;
  const int aoff = (wr*64 + lrow)*32 + kb*8;
  const int boff = (wc*64 + lrow)*32 + kb*8;

  f32x4 acc[4][4];
  #pragma unroll
  for (int i = 0; i < 4; i++)
    #pragma unroll
    for (int j = 0; j < 4; j++) acc[i][j] = (f32x4){0.f,0.f,0.f,0.f};

  for (int k0 = 0; k0 < DH0; k0 += 32){
    __syncthreads();
    stage_tile(H0h, DH0, rt0, k0, Ah, l, w);
    stage_tile(H0l, DH0, rt0, k0, Al, l, w);
    stage_tile(W1h, DH0, n0, k0, Bh, l, w);
    stage_tile(W1l, DH0, n0, k0, Bl, l, w);
    __syncthreads();
    bf16x8 a_h[4], a_l[4], b_h[4], b_l[4];
    #pragma unroll
    for (int i = 0; i < 4; i++){
      a_h[i] = *(const bf16x8*)&Ah[aoff + i*512];
      a_l[i] = *(const bf16x8*)&Al[aoff + i*512];
      b_h[i] = *(const bf16x8*)&Bh[boff + i*512];
      b_l[i] = *(const bf16x8*)&Bl[boff + i*512];
    }
    #pragma unroll
    for (int i = 0; i < 4; i++)
      #pragma unroll
      for (int j = 0; j < 4; j++){
        acc[i][j] = __builtin_amdgcn_mfma_f32_16x16x32_bf16(a_h[i], b_h[j], acc[i][j], 0, 0, 0);
        acc[i][j] = __builtin_amdgcn_mfma_f32_16x16x32_bf16(a_l[i], b_h[j], acc[i][j], 0, 0, 0);
        acc[i][j] = __builtin_amdgcn_mfma_f32_16x16x32_bf16(a_h[i], b_l[j], acc[i][j], 0, 0, 0);
      }
  }

  float p[4][4];
  #pragma unroll
  for (int mi = 0; mi < 4; mi++)
    #pragma unroll
    for (int r = 0; r < 4; r++) p[mi][r] = 0.f;

  #pragma unroll
  for (int ni = 0; ni < 4; ni++){
    int n = n0 + wc*64 + ni*16 + lrow;
    float b1v = b1[n], w2v = w2[n];
    #pragma unroll
    for (int mi = 0; mi < 4; mi++)
      #pragma unroll
      for (int r = 0; r < 4; r++)
        p[mi][r] += softplusf(acc[mi][ni][r] + b1v) * w2v;
  }
  #pragma unroll
  for (int mi = 0; mi < 4; mi++)
    #pragma unroll
    for (int r = 0; r < 4; r++){
      float s = p[mi][r];
      s += __shfl_xor(s, 1);
      s += __shfl_xor(s, 2);
      s += __shfl_xor(s, 4);
      s += __shfl_xor(s, 8);
      if (lrow == 0){
        size_t t = (size_t)bc0 * DLX + rt0 + wr*64 + mi*16 + kb*4 + r;
        spart[t * 12 + blockIdx.y*2 + wc] = s;
      }
    }
}

// ---------------- final reduce ----------------
__global__ __launch_bounds__(256) void k_reduce(const float* __restrict__ spart,
                                                const float* __restrict__ b2,
                                                float* __restrict__ out){
  int bc = blockIdx.x, tid = threadIdx.x;
  const float* p = spart + ((size_t)bc * DLX + tid) * 12;
  float s = 0.0f;
  #pragma unroll
  for (int j = 0; j < 12; j++) s += p[j];
  __shared__ float red[256];
  red[tid] = s;
  __syncthreads();
  for (int off = 128; off > 0; off >>= 1){
    if (tid < off) red[tid] += red[tid + off];
    __syncthreads();
  }
  if (tid == 0) out[bc] = red[0] + 256.0f * b2[0];
}

extern "C" void kernel_launch(void* const* d_in, const int* in_sizes, int n_in,
                              void* d_out, int out_size, void* d_ws, size_t ws_size,
                              hipStream_t stream){
  const float* xs = (const float*)d_in[0];
  const float* ys = (const float*)d_in[1];
  const float* W0 = (const float*)d_in[2];
  const float* b0 = (const float*)d_in[3];
  const float* W1 = (const float*)d_in[4];
  const float* b1 = (const float*)d_in[5];
  const float* W2 = (const float*)d_in[6];
  const float* b2 = (const float*)d_in[7];
  float* out = (float*)d_out;

  char* wsp = (char*)d_ws;
  size_t off = 0;
  auto alloc = [&](size_t bytes)->void*{
    void* p = wsp + off;
    off += (bytes + 255) & ~(size_t)255;
    return p;
  };
  unsigned long long* amax = (unsigned long long*)alloc((size_t)NTOK * 8);
  float* X0   = (float*)alloc((size_t)DB * DLX * DH0 * 4);
  float* W0xT = (float*)alloc((size_t)DD * DH0 * 4);
  unsigned short* W0yh = (unsigned short*)alloc((size_t)DH0 * DD * 2);
  unsigned short* W0yl = (unsigned short*)alloc((size_t)DH0 * DD * 2);
  unsigned short* W1h  = (unsigned short*)alloc((size_t)DH1 * DH0 * 2);
  unsigned short* W1l  = (unsigned short*)alloc((size_t)DH1 * DH0 * 2);
  float* spart = (float*)alloc((size_t)NTOK * 12 * 4);
  size_t fixed = off;
  size_t per_bc = (size_t)DLX * DH0 * 2 * 2;       // hi+lo planes per (b,c): 1.57 MB
  int G = 1;
  if (ws_size > fixed){
    long long g = (long long)((ws_size - fixed) / per_bc);
    G = (int)(g < 1 ? 1 : (g > 64 ? 64 : g));
  }
  unsigned short* H0h = (unsigned short*)alloc((size_t)G * DLX * DH0 * 2);
  unsigned short* H0l = (unsigned short*)alloc((size_t)G * DLX * DH0 * 2);

  hipMemsetAsync(amax, 0, (size_t)NTOK * 8, stream);
  k_tw0<<<dim3(24, 48), 256, 0, stream>>>(W0, W0xT);
  k_split<<<dim3(1152), 256, 0, stream>>>(W0, DH0, DD, DH0, DD, W0yh, W0yl);
  k_split<<<dim3(1152), 256, 0, stream>>>(W1, DH0, 0, DH1, DH0, W1h, W1l);
  k_scores<<<dim3(16, NBC), 256, 0, stream>>>(xs, ys, amax);
  k_x0<<<dim3(16, 12), 256, 0, stream>>>(xs, W0xT, b0, X0);
  for (int bc0 = 0; bc0 < NBC; bc0 += G){
    int g = (NBC - bc0) < G ? (NBC - bc0) : G;
    k_l0<<<dim3(2*g, 12), 256, 0, stream>>>(ys, amax, W0yh, W0yl, X0, H0h, H0l, bc0);
    k_l1<<<dim3(2*g, 6), 256, 0, stream>>>(H0h, H0l, W1h, W1l, b1, W2, spart, bc0);
  }
  k_reduce<<<NBC, 256, 0, stream>>>(spart, b2, out);
}

// Round 3
// 2495.813 us; speedup vs baseline: 3.5148x; 1.5549x over previous
//
#include <hip/hip_runtime.h>
#include <stdint.h>

#define DB   8
#define DC   64
#define DLX  256
#define DLY  256
#define DD   768
#define DH0  1536
#define DH1  768
#define NBC  (DB*DC)        // 512
#define NTOK (NBC*DLX)      // 131072
#define TAU  0.25f
#define LSTR 40             // LDS row stride in halves: 32 data + 8 pad (80B, 16B-aligned)

typedef float f32x4 __attribute__((ext_vector_type(4)));
typedef _Float16 f16x8 __attribute__((ext_vector_type(8)));
typedef _Float16 f16x4 __attribute__((ext_vector_type(4)));

__device__ __forceinline__ float softplusf(float x){
  return fmaxf(x, 0.0f) + log1pf(expf(-fabsf(x)));
}

// ---------------- W0xT transpose (fp32, for X0 GEMM) ----------------
__global__ __launch_bounds__(256) void k_tw0(const float* __restrict__ W0,
                                             float* __restrict__ W0xT){
  __shared__ float t[32][33];
  int i0 = blockIdx.x * 32, o0 = blockIdx.y * 32;
  int tx = threadIdx.x & 31, ty = threadIdx.x >> 5;
  #pragma unroll
  for (int k = 0; k < 4; k++){
    int r = ty + k * 8;
    t[r][tx] = W0[(size_t)(o0 + r) * DH0 + i0 + tx];
  }
  __syncthreads();
  #pragma unroll
  for (int k = 0; k < 4; k++){
    int r = ty + k * 8;
    W0xT[(size_t)(i0 + r) * DH0 + o0 + tx] = t[tx][r];
  }
}

// ---------------- fp32 -> f16 weight conversion ----------------
__global__ __launch_bounds__(256) void k_cvt16(const float* __restrict__ src, int ld, int off,
                                               int rows, int cols, _Float16* __restrict__ dst){
  int total = rows * (cols >> 3);
  for (int idx = blockIdx.x * 256 + threadIdx.x; idx < total; idx += gridDim.x * 256){
    int r = idx / (cols >> 3), c8 = (idx % (cols >> 3)) * 8;
    const float* s = src + (size_t)r * ld + off + c8;
    float4 f0 = *(const float4*)s, f1 = *(const float4*)(s + 4);
    f16x8 v;
    v[0]=(_Float16)f0.x; v[1]=(_Float16)f0.y; v[2]=(_Float16)f0.z; v[3]=(_Float16)f0.w;
    v[4]=(_Float16)f1.x; v[5]=(_Float16)f1.y; v[6]=(_Float16)f1.z; v[7]=(_Float16)f1.w;
    *(f16x8*)(dst + (size_t)r * cols + c8) = v;
  }
}

// ---------------- scores via f16 MFMA + exact fp32 argmax fixup ----------------
// grid (2, 512), 1024 threads. Block owns 128 x-tokens x ALL 256 y of one (b,c).
__global__ __launch_bounds__(1024, 1) void k_scores2(const float* __restrict__ xs,
                                                     const float* __restrict__ ys,
                                                     int* __restrict__ widx){
  const int bc = blockIdx.y, b = bc >> 6;
  const int x0 = blockIdx.x * 128;
  const float* X = xs + ((size_t)b * DLX + x0) * DD;
  const float* Y = ys + (size_t)bc * DLY * DD;
  __shared__ __align__(16) _Float16 As[128 * LSTR];
  __shared__ __align__(16) _Float16 Bs[256 * LSTR];
  __shared__ float rmx[128][4];
  __shared__ float gm[128];
  __shared__ unsigned short cand[128][8];
  __shared__ int ccnt[128];
  const int tid = threadIdx.x;
  const int l = tid & 63, w = tid >> 6;     // 16 waves
  const int wr = w >> 2, wc = w & 3;        // 4 x 4 wave grid; wave tile 32x64
  const int lrow = l & 15, lg = l >> 4;
  const int asr = tid >> 3, asc = (tid & 7) * 4;    // A: 128 rows x 32, 4 f32/thread
  const int bsr = tid >> 2, bsc = (tid & 3) * 8;    // B: 256 rows x 32, 8 f32/thread
  const float* xrow = X + (size_t)asr * DD + asc;
  const float* yrow = Y + (size_t)bsr * DD + bsc;

  f32x4 acc[2][4];
  #pragma unroll
  for (int i = 0; i < 2; i++)
    #pragma unroll
    for (int j = 0; j < 4; j++) acc[i][j] = (f32x4){0.f,0.f,0.f,0.f};

  for (int k0 = 0; k0 < DD; k0 += 32){
    float4 a0 = *(const float4*)(xrow + k0);
    float4 b0 = *(const float4*)(yrow + k0);
    float4 b1 = *(const float4*)(yrow + k0 + 4);
    f16x4 av; av[0]=(_Float16)a0.x; av[1]=(_Float16)a0.y; av[2]=(_Float16)a0.z; av[3]=(_Float16)a0.w;
    f16x8 bv;
    bv[0]=(_Float16)b0.x; bv[1]=(_Float16)b0.y; bv[2]=(_Float16)b0.z; bv[3]=(_Float16)b0.w;
    bv[4]=(_Float16)b1.x; bv[5]=(_Float16)b1.y; bv[6]=(_Float16)b1.z; bv[7]=(_Float16)b1.w;
    __syncthreads();
    *(f16x4*)&As[asr * LSTR + asc] = av;
    *(f16x8*)&Bs[bsr * LSTR + bsc] = bv;
    __syncthreads();
    f16x8 af[2], bf[4];
    #pragma unroll
    for (int i = 0; i < 2; i++)
      af[i] = *(const f16x8*)&As[(wr*32 + i*16 + lrow) * LSTR + lg*8];
    #pragma unroll
    for (int j = 0; j < 4; j++)
      bf[j] = *(const f16x8*)&Bs[(wc*64 + j*16 + lrow) * LSTR + lg*8];
    #pragma unroll
    for (int i = 0; i < 2; i++)
      #pragma unroll
      for (int j = 0; j < 4; j++)
        acc[i][j] = __builtin_amdgcn_mfma_f32_16x16x32_f16(af[i], bf[j], acc[i][j], 0, 0, 0);
  }

  // per-token noisy max over this wave's 64 cols, then block-wide
  #pragma unroll
  for (int i = 0; i < 2; i++)
    #pragma unroll
    for (int r = 0; r < 4; r++){
      float m = fmaxf(fmaxf(acc[i][0][r], acc[i][1][r]), fmaxf(acc[i][2][r], acc[i][3][r]));
      m = fmaxf(m, __shfl_xor(m, 1));
      m = fmaxf(m, __shfl_xor(m, 2));
      m = fmaxf(m, __shfl_xor(m, 4));
      m = fmaxf(m, __shfl_xor(m, 8));
      if (lrow == 0) rmx[wr*32 + i*16 + lg*4 + r][wc] = m;
    }
  __syncthreads();
  if (tid < 128){
    gm[tid] = fmaxf(fmaxf(rmx[tid][0], rmx[tid][1]), fmaxf(rmx[tid][2], rmx[tid][3]));
    ccnt[tid] = 0;
  }
  __syncthreads();
  // flag candidates within TAU of max (always includes the argmax itself)
  #pragma unroll
  for (int i = 0; i < 2; i++)
    #pragma unroll
    for (int r = 0; r < 4; r++){
      int t = wr*32 + i*16 + lg*4 + r;
      float thr = gm[t] - TAU;
      #pragma unroll
      for (int j = 0; j < 4; j++){
        float s = acc[i][j][r];
        if (s >= thr){
          int p = atomicAdd(&ccnt[t], 1);
          if (p < 8) cand[t][p] = (unsigned short)(wc*64 + j*16 + lrow);
        }
      }
    }
  __syncthreads();
  // resolve: wave w handles tokens w*8..w*8+7; count>1 -> exact fp32 dots
  for (int it = 0; it < 8; it++){
    int t = w * 8 + it;
    int cnt = ccnt[t];
    if (cnt == 1){
      if (l == 0) widx[(size_t)bc * DLX + x0 + t] = cand[t][0];
      continue;
    }
    const float* xr = X + (size_t)t * DD;
    float best = -1e30f; int besty = 0;
    int n = (cnt <= 8) ? cnt : 256;
    for (int p = 0; p < n; p++){
      int c = (cnt <= 8) ? (int)cand[t][p] : p;
      const float* yr = Y + (size_t)c * DD;
      float s = 0.f;
      #pragma unroll
      for (int q = 0; q < 3; q++){
        float4 xv = *(const float4*)(xr + l*12 + q*4);
        float4 yv = *(const float4*)(yr + l*12 + q*4);
        s += xv.x*yv.x + xv.y*yv.y + xv.z*yv.z + xv.w*yv.w;
      }
      s += __shfl_xor(s, 1);  s += __shfl_xor(s, 2);  s += __shfl_xor(s, 4);
      s += __shfl_xor(s, 8);  s += __shfl_xor(s, 16); s += __shfl_xor(s, 32);
      if (s > best || (s == best && c < besty)){ best = s; besty = c; }
    }
    if (l == 0) widx[(size_t)bc * DLX + x0 + t] = besty;
  }
}

// ---------------- X0 = xs @ W0xT + b0 (fp32 vector GEMM, small) ----------------
__global__ __launch_bounds__(256) void k_x0(const float* __restrict__ A,
                                            const float* __restrict__ Bt,
                                            const float* __restrict__ bias,
                                            float* __restrict__ Cout){
  const int rt0 = blockIdx.x * 128;
  const int n0  = blockIdx.y * 128;
  const int tid = threadIdx.x;
  __shared__ float Atl[16][132];
  __shared__ float Btl[16][132];
  const int sr = tid >> 1, sc = (tid & 1) * 8;
  const int br = tid >> 4, bcl = (tid & 15) * 8;
  const int trow = tid >> 4, tcol = tid & 15;
  const float* arow  = A + (size_t)(rt0 + sr) * DD;
  const float* bbase = Bt + (size_t)br * DH0 + n0 + bcl;
  float acc[8][8] = {};
  for (int k0 = 0; k0 < DD; k0 += 16){
    float4 a0  = *(const float4*)(arow + k0 + sc);
    float4 a1  = *(const float4*)(arow + k0 + sc + 4);
    float4 bv0 = *(const float4*)(bbase + (size_t)k0 * DH0);
    float4 bv1 = *(const float4*)(bbase + (size_t)k0 * DH0 + 4);
    __syncthreads();
    Atl[sc+0][sr]=a0.x; Atl[sc+1][sr]=a0.y; Atl[sc+2][sr]=a0.z; Atl[sc+3][sr]=a0.w;
    Atl[sc+4][sr]=a1.x; Atl[sc+5][sr]=a1.y; Atl[sc+6][sr]=a1.z; Atl[sc+7][sr]=a1.w;
    *(float4*)&Btl[br][bcl]     = bv0;
    *(float4*)&Btl[br][bcl + 4] = bv1;
    __syncthreads();
    #pragma unroll
    for (int kk = 0; kk < 16; kk++){
      float a_[8], b_[8];
      *(float4*)&a_[0] = *(const float4*)&Atl[kk][trow*8];
      *(float4*)&a_[4] = *(const float4*)&Atl[kk][trow*8 + 4];
      *(float4*)&b_[0] = *(const float4*)&Btl[kk][tcol*8];
      *(float4*)&b_[4] = *(const float4*)&Btl[kk][tcol*8 + 4];
      #pragma unroll
      for (int i = 0; i < 8; i++)
        #pragma unroll
        for (int j = 0; j < 8; j++)
          acc[i][j] += a_[i] * b_[j];
    }
  }
  float bl[8];
  #pragma unroll
  for (int j = 0; j < 8; j++) bl[j] = bias[n0 + tcol*8 + j];
  #pragma unroll
  for (int i = 0; i < 8; i++){
    int row = rt0 + trow*8 + i;
    float v[8];
    #pragma unroll
    for (int j = 0; j < 8; j++) v[j] = acc[i][j] + bl[j];
    *(float4*)(Cout + (size_t)row * DH0 + n0 + tcol*8)     = *(float4*)&v[0];
    *(float4*)(Cout + (size_t)row * DH0 + n0 + tcol*8 + 4) = *(float4*)&v[4];
  }
}

// ---------------- layer0: h0 = softplus(ysel @ W0y^T + X0), f16 1-pass ----------------
__global__ __launch_bounds__(256, 2) void k_l0(const float* __restrict__ ys,
        const int* __restrict__ widx,
        const _Float16* __restrict__ W0yf,
        const float* __restrict__ X0,
        _Float16* __restrict__ H0, int bc0){
  __shared__ __align__(16) _Float16 As[128 * LSTR];
  __shared__ __align__(16) _Float16 Bs[128 * LSTR];
  __shared__ int yidx[128];
  const int tid = threadIdx.x;
  const int rt0 = blockIdx.x * 128;
  const int n0  = blockIdx.y * 128;
  const int bc  = bc0 + (blockIdx.x >> 1);
  const int b   = bc >> 6;
  const int xbase = rt0 & 255;
  if (tid < 128) yidx[tid] = widx[(size_t)bc * DLX + xbase + tid];
  __syncthreads();
  const int l = tid & 63, w = tid >> 6;
  const int wr = w >> 1, wc = w & 1;
  const int lrow = l & 15, lg = l >> 4;
  const int sr = tid >> 1, sc = (tid & 1) * 16;
  const float* asrc = ys + ((size_t)bc * DLY + (size_t)yidx[sr]) * DD + sc;
  const _Float16* bsrc = W0yf + (size_t)(n0 + sr) * DD + sc;

  f32x4 acc[4][4];
  #pragma unroll
  for (int i = 0; i < 4; i++)
    #pragma unroll
    for (int j = 0; j < 4; j++) acc[i][j] = (f32x4){0.f,0.f,0.f,0.f};

  for (int k0 = 0; k0 < DD; k0 += 32){
    float4 f0 = *(const float4*)(asrc + k0);
    float4 f1 = *(const float4*)(asrc + k0 + 4);
    float4 f2 = *(const float4*)(asrc + k0 + 8);
    float4 f3 = *(const float4*)(asrc + k0 + 12);
    f16x8 av0, av1;
    av0[0]=(_Float16)f0.x; av0[1]=(_Float16)f0.y; av0[2]=(_Float16)f0.z; av0[3]=(_Float16)f0.w;
    av0[4]=(_Float16)f1.x; av0[5]=(_Float16)f1.y; av0[6]=(_Float16)f1.z; av0[7]=(_Float16)f1.w;
    av1[0]=(_Float16)f2.x; av1[1]=(_Float16)f2.y; av1[2]=(_Float16)f2.z; av1[3]=(_Float16)f2.w;
    av1[4]=(_Float16)f3.x; av1[5]=(_Float16)f3.y; av1[6]=(_Float16)f3.z; av1[7]=(_Float16)f3.w;
    f16x8 bv0 = *(const f16x8*)(bsrc + k0);
    f16x8 bv1 = *(const f16x8*)(bsrc + k0 + 8);
    __syncthreads();
    *(f16x8*)&As[sr * LSTR + sc]     = av0;
    *(f16x8*)&As[sr * LSTR + sc + 8] = av1;
    *(f16x8*)&Bs[sr * LSTR + sc]     = bv0;
    *(f16x8*)&Bs[sr * LSTR + sc + 8] = bv1;
    __syncthreads();
    f16x8 af[4], bf[4];
    #pragma unroll
    for (int i = 0; i < 4; i++){
      af[i] = *(const f16x8*)&As[(wr*64 + i*16 + lrow) * LSTR + lg*8];
      bf[i] = *(const f16x8*)&Bs[(wc*64 + i*16 + lrow) * LSTR + lg*8];
    }
    #pragma unroll
    for (int i = 0; i < 4; i++)
      #pragma unroll
      for (int j = 0; j < 4; j++)
        acc[i][j] = __builtin_amdgcn_mfma_f32_16x16x32_f16(af[i], bf[j], acc[i][j], 0, 0, 0);
  }

  #pragma unroll
  for (int mi = 0; mi < 4; mi++)
    #pragma unroll
    for (int ni = 0; ni < 4; ni++){
      int n = n0 + wc*64 + ni*16 + lrow;
      #pragma unroll
      for (int r = 0; r < 4; r++){
        int m = wr*64 + mi*16 + lg*4 + r;
        int t = rt0 + m;
        float x0v = X0[((size_t)b * DLX + (unsigned)(xbase + m)) * DH0 + n];
        float v = softplusf(acc[mi][ni][r] + x0v);
        H0[(size_t)t * DH0 + n] = (_Float16)v;
      }
    }
}

// ---------------- layer1+2: spart = softplus(h0 @ W1^T + b1) . w2, f16 1-pass ----------------
__global__ __launch_bounds__(256, 2) void k_l1(const _Float16* __restrict__ H0,
        const _Float16* __restrict__ W1f,
        const float* __restrict__ b1, const float* __restrict__ w2,
        float* __restrict__ spart, int bc0){
  __shared__ __align__(16) _Float16 As[128 * LSTR];
  __shared__ __align__(16) _Float16 Bs[128 * LSTR];
  const int tid = threadIdx.x;
  const int rt0 = blockIdx.x * 128;
  const int n0  = blockIdx.y * 128;
  const int l = tid & 63, w = tid >> 6;
  const int wr = w >> 1, wc = w & 1;
  const int lrow = l & 15, lg = l >> 4;
  const int sr = tid >> 1, sc = (tid & 1) * 16;
  const _Float16* asrc = H0  + (size_t)(rt0 + sr) * DH0 + sc;
  const _Float16* bsrc = W1f + (size_t)(n0  + sr) * DH0 + sc;

  f32x4 acc[4][4];
  #pragma unroll
  for (int i = 0; i < 4; i++)
    #pragma unroll
    for (int j = 0; j < 4; j++) acc[i][j] = (f32x4){0.f,0.f,0.f,0.f};

  for (int k0 = 0; k0 < DH0; k0 += 32){
    f16x8 av0 = *(const f16x8*)(asrc + k0);
    f16x8 av1 = *(const f16x8*)(asrc + k0 + 8);
    f16x8 bv0 = *(const f16x8*)(bsrc + k0);
    f16x8 bv1 = *(const f16x8*)(bsrc + k0 + 8);
    __syncthreads();
    *(f16x8*)&As[sr * LSTR + sc]     = av0;
    *(f16x8*)&As[sr * LSTR + sc + 8] = av1;
    *(f16x8*)&Bs[sr * LSTR + sc]     = bv0;
    *(f16x8*)&Bs[sr * LSTR + sc + 8] = bv1;
    __syncthreads();
    f16x8 af[4], bf[4];
    #pragma unroll
    for (int i = 0; i < 4; i++){
      af[i] = *(const f16x8*)&As[(wr*64 + i*16 + lrow) * LSTR + lg*8];
      bf[i] = *(const f16x8*)&Bs[(wc*64 + i*16 + lrow) * LSTR + lg*8];
    }
    #pragma unroll
    for (int i = 0; i < 4; i++)
      #pragma unroll
      for (int j = 0; j < 4; j++)
        acc[i][j] = __builtin_amdgcn_mfma_f32_16x16x32_f16(af[i], bf[j], acc[i][j], 0, 0, 0);
  }

  float p[4][4];
  #pragma unroll
  for (int mi = 0; mi < 4; mi++)
    #pragma unroll
    for (int r = 0; r < 4; r++) p[mi][r] = 0.f;
  #pragma unroll
  for (int ni = 0; ni < 4; ni++){
    int n = n0 + wc*64 + ni*16 + lrow;
    float b1v = b1[n], w2v = w2[n];
    #pragma unroll
    for (int mi = 0; mi < 4; mi++)
      #pragma unroll
      for (int r = 0; r < 4; r++)
        p[mi][r] += softplusf(acc[mi][ni][r] + b1v) * w2v;
  }
  #pragma unroll
  for (int mi = 0; mi < 4; mi++)
    #pragma unroll
    for (int r = 0; r < 4; r++){
      float s = p[mi][r];
      s += __shfl_xor(s, 1);
      s += __shfl_xor(s, 2);
      s += __shfl_xor(s, 4);
      s += __shfl_xor(s, 8);
      if (lrow == 0){
        size_t t = (size_t)bc0 * DLX + rt0 + wr*64 + mi*16 + lg*4 + r;
        spart[t * 12 + blockIdx.y*2 + wc] = s;
      }
    }
}

// ---------------- final reduce ----------------
__global__ __launch_bounds__(256) void k_reduce(const float* __restrict__ spart,
                                                const float* __restrict__ b2,
                                                float* __restrict__ out){
  int bc = blockIdx.x, tid = threadIdx.x;
  const float* p = spart + ((size_t)bc * DLX + tid) * 12;
  float s = 0.0f;
  #pragma unroll
  for (int j = 0; j < 12; j++) s += p[j];
  __shared__ float red[256];
  red[tid] = s;
  __syncthreads();
  for (int off = 128; off > 0; off >>= 1){
    if (tid < off) red[tid] += red[tid + off];
    __syncthreads();
  }
  if (tid == 0) out[bc] = red[0] + 256.0f * b2[0];
}

extern "C" void kernel_launch(void* const* d_in, const int* in_sizes, int n_in,
                              void* d_out, int out_size, void* d_ws, size_t ws_size,
                              hipStream_t stream){
  const float* xs = (const float*)d_in[0];
  const float* ys = (const float*)d_in[1];
  const float* W0 = (const float*)d_in[2];
  const float* b0 = (const float*)d_in[3];
  const float* W1 = (const float*)d_in[4];
  const float* b1 = (const float*)d_in[5];
  const float* W2 = (const float*)d_in[6];
  const float* b2 = (const float*)d_in[7];
  float* out = (float*)d_out;

  char* wsp = (char*)d_ws;
  size_t off = 0;
  auto alloc = [&](size_t bytes)->void*{
    void* p = wsp + off;
    off += (bytes + 255) & ~(size_t)255;
    return p;
  };
  int* widx = (int*)alloc((size_t)NTOK * 4);
  float* X0   = (float*)alloc((size_t)DB * DLX * DH0 * 4);
  float* W0xT = (float*)alloc((size_t)DD * DH0 * 4);
  _Float16* W0yf = (_Float16*)alloc((size_t)DH0 * DD * 2);
  _Float16* W1f  = (_Float16*)alloc((size_t)DH1 * DH0 * 2);
  float* spart = (float*)alloc((size_t)NTOK * 12 * 4);
  size_t fixed = off;
  size_t per_bc = (size_t)DLX * DH0 * 2;           // f16 h0 per (b,c): 786 KB
  int G = 1;
  if (ws_size > fixed){
    long long g = (long long)((ws_size - fixed) / per_bc);
    G = (int)(g < 1 ? 1 : (g > 64 ? 64 : g));
  }
  _Float16* H0 = (_Float16*)alloc((size_t)G * DLX * DH0 * 2);

  k_tw0<<<dim3(24, 48), 256, 0, stream>>>(W0, W0xT);
  k_cvt16<<<dim3(576), 256, 0, stream>>>(W0, DH0, DD, DH0, DD, W0yf);
  k_cvt16<<<dim3(576), 256, 0, stream>>>(W1, DH0, 0, DH1, DH0, W1f);
  k_scores2<<<dim3(2, NBC), 1024, 0, stream>>>(xs, ys, widx);
  k_x0<<<dim3(16, 12), 256, 0, stream>>>(xs, W0xT, b0, X0);
  for (int bc0 = 0; bc0 < NBC; bc0 += G){
    int g = (NBC - bc0) < G ? (NBC - bc0) : G;
    k_l0<<<dim3(2*g, 12), 256, 0, stream>>>(ys, widx, W0yf, X0, H0, bc0);
    k_l1<<<dim3(2*g, 6), 256, 0, stream>>>(H0, W1f, b1, W2, spart, bc0);
  }
  k_reduce<<<NBC, 256, 0, stream>>>(spart, b2, out);
}

// Round 4
// 2479.870 us; speedup vs baseline: 3.5374x; 1.0064x over previous
//
#include <hip/hip_runtime.h>
#include <stdint.h>

#define DB   8
#define DC   64
#define DLX  256
#define DLY  256
#define DD   768
#define DH0  1536
#define DH1  768
#define NBC  (DB*DC)        // 512
#define NTOK (NBC*DLX)      // 131072
#define TAU  0.25f
#define LSTR 40             // padded LDS stride (halves) for scores kernel

typedef float f32x4 __attribute__((ext_vector_type(4)));
typedef _Float16 f16x8 __attribute__((ext_vector_type(8)));
typedef _Float16 f16x4 __attribute__((ext_vector_type(4)));

__device__ __forceinline__ float softplusf(float x){
  return fmaxf(x, 0.0f) + log1pf(expf(-fabsf(x)));
}

// async global->LDS, 16B per lane; lds base must be wave-uniform
__device__ __forceinline__ void gload_lds16(const void* g, void* l){
  __builtin_amdgcn_global_load_lds((const __attribute__((address_space(1))) void*)g,
                                   (__attribute__((address_space(3))) void*)l,
                                   16, 0, 0);
}

// stage a [128 rows][32 halves] f16 tile (linear LDS) from row-major M (ld halves)
__device__ __forceinline__ void stage_tile(const _Float16* __restrict__ M, int ld,
                                           long long row0, int k0, _Float16* lds,
                                           int l, int w){
  #pragma unroll
  for (int i = 0; i < 2; i++){
    int blk = w*2 + i;                   // 0..7, 16 rows each
    int row = blk*16 + (l >> 2);
    int kg  = (l & 3) * 8;
    gload_lds16(M + (row0 + row)*ld + k0 + kg, lds + blk*512);
  }
}

// ---------------- W0xT transpose (fp32, for X0 GEMM) ----------------
__global__ __launch_bounds__(256) void k_tw0(const float* __restrict__ W0,
                                             float* __restrict__ W0xT){
  __shared__ float t[32][33];
  int i0 = blockIdx.x * 32, o0 = blockIdx.y * 32;
  int tx = threadIdx.x & 31, ty = threadIdx.x >> 5;
  #pragma unroll
  for (int k = 0; k < 4; k++){
    int r = ty + k * 8;
    t[r][tx] = W0[(size_t)(o0 + r) * DH0 + i0 + tx];
  }
  __syncthreads();
  #pragma unroll
  for (int k = 0; k < 4; k++){
    int r = ty + k * 8;
    W0xT[(size_t)(i0 + r) * DH0 + o0 + tx] = t[tx][r];
  }
}

// ---------------- fp32 -> f16 conversion ----------------
__global__ __launch_bounds__(256) void k_cvt16(const float* __restrict__ src, int ld, int off,
                                               int rows, int cols, _Float16* __restrict__ dst){
  int total = rows * (cols >> 3);
  for (int idx = blockIdx.x * 256 + threadIdx.x; idx < total; idx += gridDim.x * 256){
    int r = idx / (cols >> 3), c8 = (idx % (cols >> 3)) * 8;
    const float* s = src + (size_t)r * ld + off + c8;
    float4 f0 = *(const float4*)s, f1 = *(const float4*)(s + 4);
    f16x8 v;
    v[0]=(_Float16)f0.x; v[1]=(_Float16)f0.y; v[2]=(_Float16)f0.z; v[3]=(_Float16)f0.w;
    v[4]=(_Float16)f1.x; v[5]=(_Float16)f1.y; v[6]=(_Float16)f1.z; v[7]=(_Float16)f1.w;
    *(f16x8*)(dst + (size_t)r * cols + c8) = v;
  }
}

// ---------------- scores via f16 MFMA + exact fp32 argmax fixup + Ysel gather ----------------
// grid (2, 512), 1024 threads. Block owns 128 x-tokens x ALL 256 y of one (b,c).
__global__ __launch_bounds__(1024, 1) void k_scores2(const _Float16* __restrict__ xs16,
                                                     const float* __restrict__ xs,
                                                     const float* __restrict__ ys,
                                                     _Float16* __restrict__ Ysel){
  const int bc = blockIdx.y, b = bc >> 6;
  const int x0 = blockIdx.x * 128;
  const float* X = xs + ((size_t)b * DLX + x0) * DD;
  const float* Y = ys + (size_t)bc * DLY * DD;
  __shared__ __align__(16) _Float16 As[128 * LSTR];
  __shared__ __align__(16) _Float16 Bs[256 * LSTR];
  __shared__ float rmx[128][4];
  __shared__ float gm[128];
  __shared__ unsigned short cand[128][8];
  __shared__ int ccnt[128];
  const int tid = threadIdx.x;
  const int l = tid & 63, w = tid >> 6;     // 16 waves
  const int wr = w >> 2, wc = w & 3;        // 4 x 4 wave grid; wave tile 32x64
  const int lrow = l & 15, lg = l >> 4;
  const int asr = tid >> 3, asc = (tid & 7) * 4;    // A: 128 rows x 32 halves
  const int bsr = tid >> 2, bsc = (tid & 3) * 8;    // B: 256 rows x 32
  const _Float16* xrow16 = xs16 + ((size_t)b * DLX + x0 + asr) * DD + asc;
  const float* yrow = Y + (size_t)bsr * DD + bsc;

  f32x4 acc[2][4];
  #pragma unroll
  for (int i = 0; i < 2; i++)
    #pragma unroll
    for (int j = 0; j < 4; j++) acc[i][j] = (f32x4){0.f,0.f,0.f,0.f};

  for (int k0 = 0; k0 < DD; k0 += 32){
    f16x4 av = *(const f16x4*)(xrow16 + k0);
    float4 b0 = *(const float4*)(yrow + k0);
    float4 b1 = *(const float4*)(yrow + k0 + 4);
    f16x8 bv;
    bv[0]=(_Float16)b0.x; bv[1]=(_Float16)b0.y; bv[2]=(_Float16)b0.z; bv[3]=(_Float16)b0.w;
    bv[4]=(_Float16)b1.x; bv[5]=(_Float16)b1.y; bv[6]=(_Float16)b1.z; bv[7]=(_Float16)b1.w;
    __syncthreads();
    *(f16x4*)&As[asr * LSTR + asc] = av;
    *(f16x8*)&Bs[bsr * LSTR + bsc] = bv;
    __syncthreads();
    f16x8 af[2], bf[4];
    #pragma unroll
    for (int i = 0; i < 2; i++)
      af[i] = *(const f16x8*)&As[(wr*32 + i*16 + lrow) * LSTR + lg*8];
    #pragma unroll
    for (int j = 0; j < 4; j++)
      bf[j] = *(const f16x8*)&Bs[(wc*64 + j*16 + lrow) * LSTR + lg*8];
    #pragma unroll
    for (int i = 0; i < 2; i++)
      #pragma unroll
      for (int j = 0; j < 4; j++)
        acc[i][j] = __builtin_amdgcn_mfma_f32_16x16x32_f16(af[i], bf[j], acc[i][j], 0, 0, 0);
  }

  #pragma unroll
  for (int i = 0; i < 2; i++)
    #pragma unroll
    for (int r = 0; r < 4; r++){
      float m = fmaxf(fmaxf(acc[i][0][r], acc[i][1][r]), fmaxf(acc[i][2][r], acc[i][3][r]));
      m = fmaxf(m, __shfl_xor(m, 1));
      m = fmaxf(m, __shfl_xor(m, 2));
      m = fmaxf(m, __shfl_xor(m, 4));
      m = fmaxf(m, __shfl_xor(m, 8));
      if (lrow == 0) rmx[wr*32 + i*16 + lg*4 + r][wc] = m;
    }
  __syncthreads();
  if (tid < 128){
    gm[tid] = fmaxf(fmaxf(rmx[tid][0], rmx[tid][1]), fmaxf(rmx[tid][2], rmx[tid][3]));
    ccnt[tid] = 0;
  }
  __syncthreads();
  #pragma unroll
  for (int i = 0; i < 2; i++)
    #pragma unroll
    for (int r = 0; r < 4; r++){
      int t = wr*32 + i*16 + lg*4 + r;
      float thr = gm[t] - TAU;
      #pragma unroll
      for (int j = 0; j < 4; j++){
        float s = acc[i][j][r];
        if (s >= thr){
          int p = atomicAdd(&ccnt[t], 1);
          if (p < 8) cand[t][p] = (unsigned short)(wc*64 + j*16 + lrow);
        }
      }
    }
  __syncthreads();
  // resolve + gather: wave w handles tokens w*8..w*8+7
  for (int it = 0; it < 8; it++){
    int t = w * 8 + it;
    int cnt = ccnt[t];
    int by;
    if (cnt == 1){
      by = cand[t][0];
    } else {
      const float* xr = X + (size_t)t * DD;
      float best = -1e30f; int besty = 0;
      int n = (cnt <= 8) ? cnt : 256;
      for (int p = 0; p < n; p++){
        int c = (cnt <= 8) ? (int)cand[t][p] : p;
        const float* yr = Y + (size_t)c * DD;
        float s = 0.f;
        #pragma unroll
        for (int q = 0; q < 3; q++){
          float4 xv = *(const float4*)(xr + l*12 + q*4);
          float4 yv = *(const float4*)(yr + l*12 + q*4);
          s += xv.x*yv.x + xv.y*yv.y + xv.z*yv.z + xv.w*yv.w;
        }
        s += __shfl_xor(s, 1);  s += __shfl_xor(s, 2);  s += __shfl_xor(s, 4);
        s += __shfl_xor(s, 8);  s += __shfl_xor(s, 16); s += __shfl_xor(s, 32);
        if (s > best || (s == best && c < besty)){ best = s; besty = c; }
      }
      by = besty;
    }
    const float* yr = Y + (size_t)by * DD;
    _Float16* dst = Ysel + ((size_t)bc * DLX + x0 + t) * DD;
    #pragma unroll
    for (int q = 0; q < 3; q++){
      float4 v = *(const float4*)(yr + l*12 + q*4);
      f16x4 h; h[0]=(_Float16)v.x; h[1]=(_Float16)v.y; h[2]=(_Float16)v.z; h[3]=(_Float16)v.w;
      *(f16x4*)(dst + l*12 + q*4) = h;
    }
  }
}

// ---------------- X0 = xs @ W0xT + b0 (fp32 vector GEMM, small) ----------------
__global__ __launch_bounds__(256) void k_x0(const float* __restrict__ A,
                                            const float* __restrict__ Bt,
                                            const float* __restrict__ bias,
                                            float* __restrict__ Cout){
  const int rt0 = blockIdx.x * 128;
  const int n0  = blockIdx.y * 128;
  const int tid = threadIdx.x;
  __shared__ float Atl[16][132];
  __shared__ float Btl[16][132];
  const int sr = tid >> 1, sc = (tid & 1) * 8;
  const int br = tid >> 4, bcl = (tid & 15) * 8;
  const int trow = tid >> 4, tcol = tid & 15;
  const float* arow  = A + (size_t)(rt0 + sr) * DD;
  const float* bbase = Bt + (size_t)br * DH0 + n0 + bcl;
  float acc[8][8] = {};
  for (int k0 = 0; k0 < DD; k0 += 16){
    float4 a0  = *(const float4*)(arow + k0 + sc);
    float4 a1  = *(const float4*)(arow + k0 + sc + 4);
    float4 bv0 = *(const float4*)(bbase + (size_t)k0 * DH0);
    float4 bv1 = *(const float4*)(bbase + (size_t)k0 * DH0 + 4);
    __syncthreads();
    Atl[sc+0][sr]=a0.x; Atl[sc+1][sr]=a0.y; Atl[sc+2][sr]=a0.z; Atl[sc+3][sr]=a0.w;
    Atl[sc+4][sr]=a1.x; Atl[sc+5][sr]=a1.y; Atl[sc+6][sr]=a1.z; Atl[sc+7][sr]=a1.w;
    *(float4*)&Btl[br][bcl]     = bv0;
    *(float4*)&Btl[br][bcl + 4] = bv1;
    __syncthreads();
    #pragma unroll
    for (int kk = 0; kk < 16; kk++){
      float a_[8], b_[8];
      *(float4*)&a_[0] = *(const float4*)&Atl[kk][trow*8];
      *(float4*)&a_[4] = *(const float4*)&Atl[kk][trow*8 + 4];
      *(float4*)&b_[0] = *(const float4*)&Btl[kk][tcol*8];
      *(float4*)&b_[4] = *(const float4*)&Btl[kk][tcol*8 + 4];
      #pragma unroll
      for (int i = 0; i < 8; i++)
        #pragma unroll
        for (int j = 0; j < 8; j++)
          acc[i][j] += a_[i] * b_[j];
    }
  }
  float bl[8];
  #pragma unroll
  for (int j = 0; j < 8; j++) bl[j] = bias[n0 + tcol*8 + j];
  #pragma unroll
  for (int i = 0; i < 8; i++){
    int row = rt0 + trow*8 + i;
    float v[8];
    #pragma unroll
    for (int j = 0; j < 8; j++) v[j] = acc[i][j] + bl[j];
    *(float4*)(Cout + (size_t)row * DH0 + n0 + tcol*8)     = *(float4*)&v[0];
    *(float4*)(Cout + (size_t)row * DH0 + n0 + tcol*8 + 4) = *(float4*)&v[4];
  }
}

// ---------------- layer0: h0 = softplus(Ysel @ W0y^T + X0), f16, m97 staging ----------------
__global__ __launch_bounds__(256) void k_l0(const _Float16* __restrict__ Ysel,
        const _Float16* __restrict__ W0yf,
        const float* __restrict__ X0,
        _Float16* __restrict__ H0, int bc0){
  __shared__ __align__(16) _Float16 As[128 * 32];
  __shared__ __align__(16) _Float16 Bs[128 * 32];
  const int tid = threadIdx.x;
  const int rt0 = blockIdx.x * 128;           // chunk-local token base
  const int n0  = blockIdx.y * 128;
  const int bc  = bc0 + (blockIdx.x >> 1);
  const int b   = bc >> 6;
  const int xbase = rt0 & 255;
  const int l = tid & 63, w = tid >> 6;
  const int wr = w >> 1, wc = w & 1;
  const int lrow = l & 15, lg = l >> 4;
  const int aoff = (wr*64 + lrow)*32 + lg*8;
  const int boff = (wc*64 + lrow)*32 + lg*8;
  const long long arow0 = (long long)bc * DLX + xbase;

  f32x4 acc[4][4];
  #pragma unroll
  for (int i = 0; i < 4; i++)
    #pragma unroll
    for (int j = 0; j < 4; j++) acc[i][j] = (f32x4){0.f,0.f,0.f,0.f};

  for (int k0 = 0; k0 < DD; k0 += 32){
    __syncthreads();
    stage_tile(Ysel, DD, arow0, k0, As, l, w);
    stage_tile(W0yf, DD, n0,    k0, Bs, l, w);
    __syncthreads();
    f16x8 af[4], bf[4];
    #pragma unroll
    for (int i = 0; i < 4; i++){
      af[i] = *(const f16x8*)&As[aoff + i*512];
      bf[i] = *(const f16x8*)&Bs[boff + i*512];
    }
    #pragma unroll
    for (int i = 0; i < 4; i++)
      #pragma unroll
      for (int j = 0; j < 4; j++)
        acc[i][j] = __builtin_amdgcn_mfma_f32_16x16x32_f16(af[i], bf[j], acc[i][j], 0, 0, 0);
  }

  #pragma unroll
  for (int mi = 0; mi < 4; mi++)
    #pragma unroll
    for (int ni = 0; ni < 4; ni++){
      int n = n0 + wc*64 + ni*16 + lrow;
      #pragma unroll
      for (int r = 0; r < 4; r++){
        int m = wr*64 + mi*16 + lg*4 + r;
        int t = rt0 + m;
        float x0v = X0[((size_t)b * DLX + (unsigned)(xbase + m)) * DH0 + n];
        float v = softplusf(acc[mi][ni][r] + x0v);
        H0[(size_t)t * DH0 + n] = (_Float16)v;
      }
    }
}

// ---------------- layer1+2: spart = softplus(h0 @ W1^T + b1) . w2, f16, m97 staging ----------------
__global__ __launch_bounds__(256) void k_l1(const _Float16* __restrict__ H0,
        const _Float16* __restrict__ W1f,
        const float* __restrict__ b1, const float* __restrict__ w2,
        float* __restrict__ spart, int bc0){
  __shared__ __align__(16) _Float16 As[128 * 32];
  __shared__ __align__(16) _Float16 Bs[128 * 32];
  const int tid = threadIdx.x;
  const int rt0 = blockIdx.x * 128;
  const int n0  = blockIdx.y * 128;
  const int l = tid & 63, w = tid >> 6;
  const int wr = w >> 1, wc = w & 1;
  const int lrow = l & 15, lg = l >> 4;
  const int aoff = (wr*64 + lrow)*32 + lg*8;
  const int boff = (wc*64 + lrow)*32 + lg*8;

  f32x4 acc[4][4];
  #pragma unroll
  for (int i = 0; i < 4; i++)
    #pragma unroll
    for (int j = 0; j < 4; j++) acc[i][j] = (f32x4){0.f,0.f,0.f,0.f};

  for (int k0 = 0; k0 < DH0; k0 += 32){
    __syncthreads();
    stage_tile(H0,  DH0, rt0, k0, As, l, w);
    stage_tile(W1f, DH0, n0,  k0, Bs, l, w);
    __syncthreads();
    f16x8 af[4], bf[4];
    #pragma unroll
    for (int i = 0; i < 4; i++){
      af[i] = *(const f16x8*)&As[aoff + i*512];
      bf[i] = *(const f16x8*)&Bs[boff + i*512];
    }
    #pragma unroll
    for (int i = 0; i < 4; i++)
      #pragma unroll
      for (int j = 0; j < 4; j++)
        acc[i][j] = __builtin_amdgcn_mfma_f32_16x16x32_f16(af[i], bf[j], acc[i][j], 0, 0, 0);
  }

  float p[4][4];
  #pragma unroll
  for (int mi = 0; mi < 4; mi++)
    #pragma unroll
    for (int r = 0; r < 4; r++) p[mi][r] = 0.f;
  #pragma unroll
  for (int ni = 0; ni < 4; ni++){
    int n = n0 + wc*64 + ni*16 + lrow;
    float b1v = b1[n], w2v = w2[n];
    #pragma unroll
    for (int mi = 0; mi < 4; mi++)
      #pragma unroll
      for (int r = 0; r < 4; r++)
        p[mi][r] += softplusf(acc[mi][ni][r] + b1v) * w2v;
  }
  #pragma unroll
  for (int mi = 0; mi < 4; mi++)
    #pragma unroll
    for (int r = 0; r < 4; r++){
      float s = p[mi][r];
      s += __shfl_xor(s, 1);
      s += __shfl_xor(s, 2);
      s += __shfl_xor(s, 4);
      s += __shfl_xor(s, 8);
      if (lrow == 0){
        size_t t = (size_t)bc0 * DLX + rt0 + wr*64 + mi*16 + lg*4 + r;
        spart[t * 12 + blockIdx.y*2 + wc] = s;
      }
    }
}

// ---------------- final reduce ----------------
__global__ __launch_bounds__(256) void k_reduce(const float* __restrict__ spart,
                                                const float* __restrict__ b2,
                                                float* __restrict__ out){
  int bc = blockIdx.x, tid = threadIdx.x;
  const float* p = spart + ((size_t)bc * DLX + tid) * 12;
  float s = 0.0f;
  #pragma unroll
  for (int j = 0; j < 12; j++) s += p[j];
  __shared__ float red[256];
  red[tid] = s;
  __syncthreads();
  for (int off = 128; off > 0; off >>= 1){
    if (tid < off) red[tid] += red[tid + off];
    __syncthreads();
  }
  if (tid == 0) out[bc] = red[0] + 256.0f * b2[0];
}

extern "C" void kernel_launch(void* const* d_in, const int* in_sizes, int n_in,
                              void* d_out, int out_size, void* d_ws, size_t ws_size,
                              hipStream_t stream){
  const float* xs = (const float*)d_in[0];
  const float* ys = (const float*)d_in[1];
  const float* W0 = (const float*)d_in[2];
  const float* b0 = (const float*)d_in[3];
  const float* W1 = (const float*)d_in[4];
  const float* b1 = (const float*)d_in[5];
  const float* W2 = (const float*)d_in[6];
  const float* b2 = (const float*)d_in[7];
  float* out = (float*)d_out;

  char* wsp = (char*)d_ws;
  size_t off = 0;
  auto alloc = [&](size_t bytes)->void*{
    void* p = wsp + off;
    off += (bytes + 255) & ~(size_t)255;
    return p;
  };
  _Float16* Ysel = (_Float16*)alloc((size_t)NTOK * DD * 2);
  float* X0   = (float*)alloc((size_t)DB * DLX * DH0 * 4);
  float* W0xT = (float*)alloc((size_t)DD * DH0 * 4);
  _Float16* W0yf = (_Float16*)alloc((size_t)DH0 * DD * 2);
  _Float16* W1f  = (_Float16*)alloc((size_t)DH1 * DH0 * 2);
  _Float16* xs16 = (_Float16*)alloc((size_t)DB * DLX * DD * 2);
  float* spart = (float*)alloc((size_t)NTOK * 12 * 4);
  size_t fixed = off;
  size_t per_bc = (size_t)DLX * DH0 * 2;           // f16 h0 per (b,c): 786 KB
  int G = 1;
  if (ws_size > fixed){
    long long g = (long long)((ws_size - fixed) / per_bc);
    G = (int)(g < 1 ? 1 : (g > 64 ? 64 : g));
  }
  _Float16* H0 = (_Float16*)alloc((size_t)G * DLX * DH0 * 2);

  k_tw0<<<dim3(24, 48), 256, 0, stream>>>(W0, W0xT);
  k_cvt16<<<dim3(576), 256, 0, stream>>>(W0, DH0, DD, DH0, DD, W0yf);
  k_cvt16<<<dim3(576), 256, 0, stream>>>(W1, DH0, 0, DH1, DH0, W1f);
  k_cvt16<<<dim3(768), 256, 0, stream>>>(xs, DD, 0, DB*DLX, DD, xs16);
  k_scores2<<<dim3(2, NBC), 1024, 0, stream>>>(xs16, xs, ys, Ysel);
  k_x0<<<dim3(16, 12), 256, 0, stream>>>(xs, W0xT, b0, X0);
  for (int bc0 = 0; bc0 < NBC; bc0 += G){
    int g = (NBC - bc0) < G ? (NBC - bc0) : G;
    k_l0<<<dim3(2*g, 12), 256, 0, stream>>>(Ysel, W0yf, X0, H0, bc0);
    k_l1<<<dim3(2*g, 6), 256, 0, stream>>>(H0, W1f, b1, W2, spart, bc0);
  }
  k_reduce<<<NBC, 256, 0, stream>>>(spart, b2, out);
}

// Round 6
// 1360.855 us; speedup vs baseline: 6.4462x; 1.8223x over previous
//
#include <hip/hip_runtime.h>
#include <stdint.h>

#define DB   8
#define DC   64
#define DLX  256
#define DLY  256
#define DD   768
#define DH0  1536
#define DH1  768
#define NBC  (DB*DC)        // 512
#define NTOK (NBC*DLX)      // 131072
#define TAU  0.25f

typedef float f32x4 __attribute__((ext_vector_type(4)));
typedef _Float16 f16x8 __attribute__((ext_vector_type(8)));
typedef _Float16 f16x4 __attribute__((ext_vector_type(4)));

// fast softplus via hw exp2/log2: max(x,0) + ln2*log2(1 + 2^(-|x|*log2e))
__device__ __forceinline__ float softplusf(float x){
  float t = __builtin_amdgcn_exp2f(-fabsf(x) * 1.44269504f);
  return fmaxf(x, 0.0f) + 0.69314718f * __builtin_amdgcn_logf(1.0f + t);
}

// async global->LDS, 16B per lane; lds base wave-uniform, global addr per-lane
__device__ __forceinline__ void gload_lds16(const void* g, void* l){
  __builtin_amdgcn_global_load_lds((const __attribute__((address_space(1))) void*)g,
                                   (__attribute__((address_space(3))) void*)l,
                                   16, 0, 0);
}

// ---------------- fp32 -> f16 conversion (strided submatrix) ----------------
__global__ __launch_bounds__(256) void k_cvt16(const float* __restrict__ src, int ld, int off,
                                               int rows, int cols, _Float16* __restrict__ dst){
  int total = rows * (cols >> 3);
  for (int idx = blockIdx.x * 256 + threadIdx.x; idx < total; idx += gridDim.x * 256){
    int r = idx / (cols >> 3), c8 = (idx % (cols >> 3)) * 8;
    const float* s = src + (size_t)r * ld + off + c8;
    float4 f0 = *(const float4*)s, f1 = *(const float4*)(s + 4);
    f16x8 v;
    v[0]=(_Float16)f0.x; v[1]=(_Float16)f0.y; v[2]=(_Float16)f0.z; v[3]=(_Float16)f0.w;
    v[4]=(_Float16)f1.x; v[5]=(_Float16)f1.y; v[6]=(_Float16)f1.z; v[7]=(_Float16)f1.w;
    *(f16x8*)(dst + (size_t)r * cols + c8) = v;
  }
}

// ---------------- scores: f16 MFMA + exact fp32 argmax fixup -> widx ----------------
// grid (2, 512), 1024 threads. Block: 128 x-tokens x ALL 256 y of one (b,c).
__global__ __launch_bounds__(1024, 1) void k_scores3(const _Float16* __restrict__ xs16,
                                                     const _Float16* __restrict__ ys16,
                                                     const float* __restrict__ xs,
                                                     const float* __restrict__ ys,
                                                     int* __restrict__ widx){
  const int bc = blockIdx.y, b = bc >> 6;
  const int x0 = blockIdx.x * 128;
  const float* X = xs + ((size_t)b * DLX + x0) * DD;
  const float* Y = ys + (size_t)bc * DLY * DD;
  __shared__ __align__(16) _Float16 As[128 * 32];
  __shared__ __align__(16) _Float16 Bs[256 * 32];
  __shared__ float rmx[128][4];
  __shared__ float gm[128];
  __shared__ unsigned short cand[128][8];
  __shared__ int ccnt[128];
  const int tid = threadIdx.x;
  const int l = tid & 63, w = tid >> 6;     // 16 waves
  const int wr = w >> 2, wc = w & 3;        // wave tile 32x64
  const int lrow = l & 15, lg = l >> 4;
  const int srow = l >> 2, kg = (l & 3) * 8;
  const _Float16* srcB = ys16 + ((size_t)bc * DLY + w*16 + srow) * DD + kg;
  const _Float16* srcA = xs16 + ((size_t)b * DLX + x0 + (w & 7)*16 + srow) * DD + kg;

  f32x4 acc[2][4];
  #pragma unroll
  for (int i = 0; i < 2; i++)
    #pragma unroll
    for (int j = 0; j < 4; j++) acc[i][j] = (f32x4){0.f,0.f,0.f,0.f};

  for (int k0 = 0; k0 < DD; k0 += 32){
    __syncthreads();
    gload_lds16(srcB + k0, Bs + w*512);
    if (w < 8) gload_lds16(srcA + k0, As + w*512);
    __syncthreads();
    f16x8 af[2], bf[4];
    #pragma unroll
    for (int i = 0; i < 2; i++)
      af[i] = *(const f16x8*)&As[(wr*32 + i*16 + lrow)*32 + lg*8];
    #pragma unroll
    for (int j = 0; j < 4; j++)
      bf[j] = *(const f16x8*)&Bs[(wc*64 + j*16 + lrow)*32 + lg*8];
    #pragma unroll
    for (int i = 0; i < 2; i++)
      #pragma unroll
      for (int j = 0; j < 4; j++)
        acc[i][j] = __builtin_amdgcn_mfma_f32_16x16x32_f16(af[i], bf[j], acc[i][j], 0, 0, 0);
  }

  // per-token noisy max
  #pragma unroll
  for (int i = 0; i < 2; i++)
    #pragma unroll
    for (int r = 0; r < 4; r++){
      float m = fmaxf(fmaxf(acc[i][0][r], acc[i][1][r]), fmaxf(acc[i][2][r], acc[i][3][r]));
      m = fmaxf(m, __shfl_xor(m, 1));
      m = fmaxf(m, __shfl_xor(m, 2));
      m = fmaxf(m, __shfl_xor(m, 4));
      m = fmaxf(m, __shfl_xor(m, 8));
      if (lrow == 0) rmx[wr*32 + i*16 + lg*4 + r][wc] = m;
    }
  __syncthreads();
  if (tid < 128){
    gm[tid] = fmaxf(fmaxf(rmx[tid][0], rmx[tid][1]), fmaxf(rmx[tid][2], rmx[tid][3]));
    ccnt[tid] = 0;
  }
  __syncthreads();
  #pragma unroll
  for (int i = 0; i < 2; i++)
    #pragma unroll
    for (int r = 0; r < 4; r++){
      int t = wr*32 + i*16 + lg*4 + r;
      float thr = gm[t] - TAU;
      #pragma unroll
      for (int j = 0; j < 4; j++){
        float s = acc[i][j][r];
        if (s >= thr){
          int p = atomicAdd(&ccnt[t], 1);
          if (p < 8) cand[t][p] = (unsigned short)(wc*64 + j*16 + lrow);
        }
      }
    }
  __syncthreads();
  // resolve: wave w handles tokens w*8..w*8+7; cnt>1 -> exact fp32 dots
  for (int it = 0; it < 8; it++){
    int t = w * 8 + it;
    int cnt = ccnt[t];
    int by;
    if (cnt == 1){
      by = cand[t][0];
    } else {
      const float* xr = X + (size_t)t * DD;
      float best = -1e30f; int besty = 0;
      int n = (cnt <= 8) ? cnt : 256;
      for (int p = 0; p < n; p++){
        int c = (cnt <= 8) ? (int)cand[t][p] : p;
        const float* yr = Y + (size_t)c * DD;
        float s = 0.f;
        #pragma unroll
        for (int q = 0; q < 3; q++){
          float4 xv = *(const float4*)(xr + l*12 + q*4);
          float4 yv = *(const float4*)(yr + l*12 + q*4);
          s += xv.x*yv.x + xv.y*yv.y + xv.z*yv.z + xv.w*yv.w;
        }
        s += __shfl_xor(s, 1);  s += __shfl_xor(s, 2);  s += __shfl_xor(s, 4);
        s += __shfl_xor(s, 8);  s += __shfl_xor(s, 16); s += __shfl_xor(s, 32);
        if (s > best || (s == best && c < besty)){ best = s; besty = c; }
      }
      by = besty;
    }
    if (l == 0) widx[(size_t)bc * DLX + x0 + t] = by;
  }
}

// ---------------- unified 128x128 f16 MFMA GEMM (m97 staging) ----------------
// MODE 0: X0 = xs16 @ W0x^T + b0            -> f32 X0      (grid 16 x 12)
// MODE 1: H0 = softplus(ys16[widx] @ W0y^T + X0) -> f16 H0 (grid 1024 x 12)
// MODE 2: spart = softplus(H0 @ W1^T + b1) . w2  -> f32    (grid 1024 x 6)
template<int MODE>
__global__ __launch_bounds__(256) void k_gemm16(const _Float16* __restrict__ A,
        const _Float16* __restrict__ B,
        const int* __restrict__ widx,
        const float* __restrict__ X0,
        const float* __restrict__ bias,
        const float* __restrict__ w2,
        float* __restrict__ outF,
        _Float16* __restrict__ outH){
  constexpr int K = (MODE == 2) ? DH0 : DD;
  __shared__ __align__(16) _Float16 As[128 * 32];
  __shared__ __align__(16) _Float16 Bs[128 * 32];
  const int tid = threadIdx.x;
  const int rt0 = blockIdx.x * 128;
  const int n0  = blockIdx.y * 128;
  const int l = tid & 63, w = tid >> 6;
  const int wr = w >> 1, wc = w & 1;
  const int lrow = l & 15, lg = l >> 4;
  const int r_a = (w*2)*16 + (l >> 2);     // staging row, first block
  const int r_b = (w*2+1)*16 + (l >> 2);   // staging row, second block
  const int kg = (l & 3) * 8;

  const _Float16 *srcA0, *srcA1;
  if constexpr (MODE == 1){
    const int bc = blockIdx.x >> 1, xb = (blockIdx.x & 1) * 128;
    int y0i = widx[bc * DLX + xb + r_a];
    int y1i = widx[bc * DLX + xb + r_b];
    srcA0 = A + ((size_t)bc * DLY + y0i) * DD + kg;
    srcA1 = A + ((size_t)bc * DLY + y1i) * DD + kg;
  } else {
    srcA0 = A + (size_t)(rt0 + r_a) * K + kg;
    srcA1 = A + (size_t)(rt0 + r_b) * K + kg;
  }
  const _Float16* srcB0 = B + (size_t)(n0 + r_a) * K + kg;
  const _Float16* srcB1 = B + (size_t)(n0 + r_b) * K + kg;

  f32x4 acc[4][4];
  #pragma unroll
  for (int i = 0; i < 4; i++)
    #pragma unroll
    for (int j = 0; j < 4; j++) acc[i][j] = (f32x4){0.f,0.f,0.f,0.f};

  for (int k0 = 0; k0 < K; k0 += 32){
    __syncthreads();
    gload_lds16(srcA0 + k0, As + (w*2)*512);
    gload_lds16(srcA1 + k0, As + (w*2+1)*512);
    gload_lds16(srcB0 + k0, Bs + (w*2)*512);
    gload_lds16(srcB1 + k0, Bs + (w*2+1)*512);
    __syncthreads();
    f16x8 af[4], bf[4];
    #pragma unroll
    for (int i = 0; i < 4; i++){
      af[i] = *(const f16x8*)&As[(wr*64 + i*16 + lrow)*32 + lg*8];
      bf[i] = *(const f16x8*)&Bs[(wc*64 + i*16 + lrow)*32 + lg*8];
    }
    #pragma unroll
    for (int i = 0; i < 4; i++)
      #pragma unroll
      for (int j = 0; j < 4; j++)
        acc[i][j] = __builtin_amdgcn_mfma_f32_16x16x32_f16(af[i], bf[j], acc[i][j], 0, 0, 0);
  }

  if constexpr (MODE == 0){
    #pragma unroll
    for (int mi = 0; mi < 4; mi++)
      #pragma unroll
      for (int ni = 0; ni < 4; ni++){
        int n = n0 + wc*64 + ni*16 + lrow;
        float bv = bias[n];
        #pragma unroll
        for (int r = 0; r < 4; r++){
          int m = wr*64 + mi*16 + lg*4 + r;
          outF[(size_t)(rt0 + m) * DH0 + n] = acc[mi][ni][r] + bv;
        }
      }
  } else if constexpr (MODE == 1){
    const int bc = blockIdx.x >> 1, xb = (blockIdx.x & 1) * 128;
    const int b = bc >> 6;
    #pragma unroll
    for (int mi = 0; mi < 4; mi++)
      #pragma unroll
      for (int ni = 0; ni < 4; ni++){
        int n = n0 + wc*64 + ni*16 + lrow;
        #pragma unroll
        for (int r = 0; r < 4; r++){
          int m = wr*64 + mi*16 + lg*4 + r;
          float x0v = X0[((size_t)b * DLX + xb + m) * DH0 + n];
          float v = softplusf(acc[mi][ni][r] + x0v);
          outH[(size_t)(rt0 + m) * DH0 + n] = (_Float16)v;
        }
      }
  } else {
    float p[4][4];
    #pragma unroll
    for (int mi = 0; mi < 4; mi++)
      #pragma unroll
      for (int r = 0; r < 4; r++) p[mi][r] = 0.f;
    #pragma unroll
    for (int ni = 0; ni < 4; ni++){
      int n = n0 + wc*64 + ni*16 + lrow;
      float b1v = bias[n], w2v = w2[n];
      #pragma unroll
      for (int mi = 0; mi < 4; mi++)
        #pragma unroll
        for (int r = 0; r < 4; r++)
          p[mi][r] += softplusf(acc[mi][ni][r] + b1v) * w2v;
    }
    #pragma unroll
    for (int mi = 0; mi < 4; mi++)
      #pragma unroll
      for (int r = 0; r < 4; r++){
        float s = p[mi][r];
        s += __shfl_xor(s, 1);
        s += __shfl_xor(s, 2);
        s += __shfl_xor(s, 4);
        s += __shfl_xor(s, 8);
        if (lrow == 0){
          size_t t = (size_t)rt0 + wr*64 + mi*16 + lg*4 + r;
          outF[t * 12 + blockIdx.y*2 + wc] = s;
        }
      }
  }
}

// ---------------- final reduce ----------------
__global__ __launch_bounds__(256) void k_reduce(const float* __restrict__ spart,
                                                const float* __restrict__ b2,
                                                float* __restrict__ out){
  int bc = blockIdx.x, tid = threadIdx.x;
  const float* p = spart + ((size_t)bc * DLX + tid) * 12;
  float s = 0.0f;
  #pragma unroll
  for (int j = 0; j < 12; j++) s += p[j];
  __shared__ float red[256];
  red[tid] = s;
  __syncthreads();
  for (int off = 128; off > 0; off >>= 1){
    if (tid < off) red[tid] += red[tid + off];
    __syncthreads();
  }
  if (tid == 0) out[bc] = red[0] + 256.0f * b2[0];
}

extern "C" void kernel_launch(void* const* d_in, const int* in_sizes, int n_in,
                              void* d_out, int out_size, void* d_ws, size_t ws_size,
                              hipStream_t stream){
  const float* xs = (const float*)d_in[0];
  const float* ys = (const float*)d_in[1];
  const float* W0 = (const float*)d_in[2];
  const float* b0 = (const float*)d_in[3];
  const float* W1 = (const float*)d_in[4];
  const float* b1 = (const float*)d_in[5];
  const float* W2 = (const float*)d_in[6];
  const float* b2 = (const float*)d_in[7];
  float* out = (float*)d_out;

  char* wsp = (char*)d_ws;
  size_t off = 0;
  auto alloc = [&](size_t bytes)->void*{
    void* p = wsp + off;
    off += (bytes + 255) & ~(size_t)255;
    return p;
  };
  int* widx        = (int*)alloc((size_t)NTOK * 4);
  _Float16* ys16   = (_Float16*)alloc((size_t)NBC * DLY * DD * 2);   // 201 MB
  _Float16* xs16   = (_Float16*)alloc((size_t)DB * DLX * DD * 2);
  _Float16* W0xf   = (_Float16*)alloc((size_t)DH0 * DD * 2);
  _Float16* W0yf   = (_Float16*)alloc((size_t)DH0 * DD * 2);
  _Float16* W1f    = (_Float16*)alloc((size_t)DH1 * DH0 * 2);
  float* X0        = (float*)alloc((size_t)DB * DLX * DH0 * 4);      // 12.6 MB
  float* spart     = (float*)alloc((size_t)NTOK * 12 * 4);           // 6.3 MB
  _Float16* H0     = (_Float16*)alloc((size_t)NTOK * DH0 * 2);       // 402 MB

  k_cvt16<<<dim3(576),  256, 0, stream>>>(W0, DH0, 0,  DH0, DD, W0xf);
  k_cvt16<<<dim3(576),  256, 0, stream>>>(W0, DH0, DD, DH0, DD, W0yf);
  k_cvt16<<<dim3(576),  256, 0, stream>>>(W1, DH0, 0,  DH1, DH0, W1f);
  k_cvt16<<<dim3(768),  256, 0, stream>>>(xs, DD, 0, DB*DLX, DD, xs16);
  k_cvt16<<<dim3(4096), 256, 0, stream>>>(ys, DD, 0, NBC*DLY, DD, ys16);
  k_scores3<<<dim3(2, NBC), 1024, 0, stream>>>(xs16, ys16, xs, ys, widx);
  k_gemm16<0><<<dim3(16, 12),   256, 0, stream>>>(xs16, W0xf, nullptr, nullptr, b0, nullptr, X0, nullptr);
  k_gemm16<1><<<dim3(1024, 12), 256, 0, stream>>>(ys16, W0yf, widx, X0, nullptr, nullptr, nullptr, H0);
  k_gemm16<2><<<dim3(1024, 6),  256, 0, stream>>>(H0, W1f, nullptr, nullptr, b1, W2, spart, nullptr);
  k_reduce<<<NBC, 256, 0, stream>>>(spart, b2, out);
}

// Round 7
// 1189.970 us; speedup vs baseline: 7.3719x; 1.1436x over previous
//
#include <hip/hip_runtime.h>
#include <stdint.h>

#define DB   8
#define DC   64
#define DLX  256
#define DLY  256
#define DD   768
#define DH0  1536
#define DH1  768
#define NBC  (DB*DC)        // 512
#define NTOK (NBC*DLX)      // 131072
#define TAU  0.25f

typedef float f32x4 __attribute__((ext_vector_type(4)));
typedef _Float16 f16x8 __attribute__((ext_vector_type(8)));
typedef _Float16 f16x4 __attribute__((ext_vector_type(4)));

// fast softplus via hw exp2/log2
__device__ __forceinline__ float softplusf(float x){
  float t = __builtin_amdgcn_exp2f(-fabsf(x) * 1.44269504f);
  return fmaxf(x, 0.0f) + 0.69314718f * __builtin_amdgcn_logf(1.0f + t);
}

// async global->LDS, 16B per lane; lds base wave-uniform (linear dest)
__device__ __forceinline__ void gload_lds16(const void* g, void* l){
  __builtin_amdgcn_global_load_lds((const __attribute__((address_space(1))) void*)g,
                                   (__attribute__((address_space(3))) void*)l,
                                   16, 0, 0);
}

// LDS swizzle (T2, both-sides): LDS[r][s] holds global[r][s ^ (r&3)] (16B slots).
// stage source col (halves): ((l&3) ^ ((l>>2)&3)) * 8 ; read col: (lg ^ (lrow&3)) * 8

// ---------------- fp32 -> f16 conversion (strided submatrix) ----------------
__global__ __launch_bounds__(256) void k_cvt16(const float* __restrict__ src, int ld, int off,
                                               int rows, int cols, _Float16* __restrict__ dst){
  int total = rows * (cols >> 3);
  for (int idx = blockIdx.x * 256 + threadIdx.x; idx < total; idx += gridDim.x * 256){
    int r = idx / (cols >> 3), c8 = (idx % (cols >> 3)) * 8;
    const float* s = src + (size_t)r * ld + off + c8;
    float4 f0 = *(const float4*)s, f1 = *(const float4*)(s + 4);
    f16x8 v;
    v[0]=(_Float16)f0.x; v[1]=(_Float16)f0.y; v[2]=(_Float16)f0.z; v[3]=(_Float16)f0.w;
    v[4]=(_Float16)f1.x; v[5]=(_Float16)f1.y; v[6]=(_Float16)f1.z; v[7]=(_Float16)f1.w;
    *(f16x8*)(dst + (size_t)r * cols + c8) = v;
  }
}

// ---------------- scores: f16 MFMA + exact fp32 argmax fixup -> widx ----------------
// grid (2, 512), 1024 threads. Block: 128 x-tokens x ALL 256 y of one (b,c).
__global__ __launch_bounds__(1024, 1) void k_scores3(const _Float16* __restrict__ xs16,
                                                     const _Float16* __restrict__ ys16,
                                                     const float* __restrict__ xs,
                                                     const float* __restrict__ ys,
                                                     int* __restrict__ widx){
  const int bc = blockIdx.y, b = bc >> 6;
  const int x0 = blockIdx.x * 128;
  const float* X = xs + ((size_t)b * DLX + x0) * DD;
  const float* Y = ys + (size_t)bc * DLY * DD;
  __shared__ __align__(16) _Float16 As[128 * 32];
  __shared__ __align__(16) _Float16 Bs[256 * 32];
  __shared__ float rmx[128][4];
  __shared__ float gm[128];
  __shared__ unsigned short cand[128][8];
  __shared__ int ccnt[128];
  const int tid = threadIdx.x;
  const int l = tid & 63, w = tid >> 6;     // 16 waves
  const int wr = w >> 2, wc = w & 3;        // wave tile 32x64
  const int lrow = l & 15, lg = l >> 4;
  const int kq = (lg ^ (lrow & 3)) * 8;     // swizzled read col (halves)
  const int srow = l >> 2;
  const int kg = (((l & 3) ^ ((l >> 2) & 3))) * 8;  // swizzled source col
  const _Float16* srcB = ys16 + ((size_t)bc * DLY + w*16 + srow) * DD + kg;
  const _Float16* srcA = xs16 + ((size_t)b * DLX + x0 + (w & 7)*16 + srow) * DD + kg;

  f32x4 acc[2][4];
  #pragma unroll
  for (int i = 0; i < 2; i++)
    #pragma unroll
    for (int j = 0; j < 4; j++) acc[i][j] = (f32x4){0.f,0.f,0.f,0.f};

  for (int k0 = 0; k0 < DD; k0 += 32){
    __syncthreads();
    gload_lds16(srcB + k0, Bs + w*512);
    if (w < 8) gload_lds16(srcA + k0, As + w*512);
    __syncthreads();
    f16x8 af[2], bf[4];
    #pragma unroll
    for (int i = 0; i < 2; i++)
      af[i] = *(const f16x8*)&As[(wr*32 + i*16 + lrow)*32 + kq];
    #pragma unroll
    for (int j = 0; j < 4; j++)
      bf[j] = *(const f16x8*)&Bs[(wc*64 + j*16 + lrow)*32 + kq];
    #pragma unroll
    for (int i = 0; i < 2; i++)
      #pragma unroll
      for (int j = 0; j < 4; j++)
        acc[i][j] = __builtin_amdgcn_mfma_f32_16x16x32_f16(af[i], bf[j], acc[i][j], 0, 0, 0);
  }

  // per-token noisy max
  #pragma unroll
  for (int i = 0; i < 2; i++)
    #pragma unroll
    for (int r = 0; r < 4; r++){
      float m = fmaxf(fmaxf(acc[i][0][r], acc[i][1][r]), fmaxf(acc[i][2][r], acc[i][3][r]));
      m = fmaxf(m, __shfl_xor(m, 1));
      m = fmaxf(m, __shfl_xor(m, 2));
      m = fmaxf(m, __shfl_xor(m, 4));
      m = fmaxf(m, __shfl_xor(m, 8));
      if (lrow == 0) rmx[wr*32 + i*16 + lg*4 + r][wc] = m;
    }
  __syncthreads();
  if (tid < 128){
    gm[tid] = fmaxf(fmaxf(rmx[tid][0], rmx[tid][1]), fmaxf(rmx[tid][2], rmx[tid][3]));
    ccnt[tid] = 0;
  }
  __syncthreads();
  #pragma unroll
  for (int i = 0; i < 2; i++)
    #pragma unroll
    for (int r = 0; r < 4; r++){
      int t = wr*32 + i*16 + lg*4 + r;
      float thr = gm[t] - TAU;
      #pragma unroll
      for (int j = 0; j < 4; j++){
        float s = acc[i][j][r];
        if (s >= thr){
          int p = atomicAdd(&ccnt[t], 1);
          if (p < 8) cand[t][p] = (unsigned short)(wc*64 + j*16 + lrow);
        }
      }
    }
  __syncthreads();
  // resolve: wave w handles tokens w*8..w*8+7; cnt>1 -> exact fp32 dots
  for (int it = 0; it < 8; it++){
    int t = w * 8 + it;
    int cnt = ccnt[t];
    int by;
    if (cnt == 1){
      by = cand[t][0];
    } else {
      const float* xr = X + (size_t)t * DD;
      float best = -1e30f; int besty = 0;
      int n = (cnt <= 8) ? cnt : 256;
      for (int p = 0; p < n; p++){
        int c = (cnt <= 8) ? (int)cand[t][p] : p;
        const float* yr = Y + (size_t)c * DD;
        float s = 0.f;
        #pragma unroll
        for (int q = 0; q < 3; q++){
          float4 xv = *(const float4*)(xr + l*12 + q*4);
          float4 yv = *(const float4*)(yr + l*12 + q*4);
          s += xv.x*yv.x + xv.y*yv.y + xv.z*yv.z + xv.w*yv.w;
        }
        s += __shfl_xor(s, 1);  s += __shfl_xor(s, 2);  s += __shfl_xor(s, 4);
        s += __shfl_xor(s, 8);  s += __shfl_xor(s, 16); s += __shfl_xor(s, 32);
        if (s > best || (s == best && c < besty)){ best = s; besty = c; }
      }
      by = besty;
    }
    if (l == 0) widx[(size_t)bc * DLX + x0 + t] = by;
  }
}

// ---------------- unified 128x128 f16 MFMA GEMM (m97 staging, swizzled LDS) ----------------
// n-tile on blockIdx.x (fastest) so blocks sharing an A-panel dispatch adjacently.
// MODE 0: X0 = xs16 @ W0x^T + b0                 (grid 12 x 16)
// MODE 1: H0 = softplus(ys16[widx] @ W0y^T + X0) (grid 12 x 1024)
// MODE 2: spart = softplus(H0 @ W1^T + b1) . w2  (grid 6 x 1024)
template<int MODE>
__global__ __launch_bounds__(256) void k_gemm16(const _Float16* __restrict__ A,
        const _Float16* __restrict__ B,
        const int* __restrict__ widx,
        const float* __restrict__ X0,
        const float* __restrict__ bias,
        const float* __restrict__ w2,
        float* __restrict__ outF,
        _Float16* __restrict__ outH){
  constexpr int K = (MODE == 2) ? DH0 : DD;
  __shared__ __align__(16) _Float16 As[128 * 32];
  __shared__ __align__(16) _Float16 Bs[128 * 32];
  const int tid = threadIdx.x;
  const int n0  = blockIdx.x * 128;
  const int rt0 = blockIdx.y * 128;
  const int l = tid & 63, w = tid >> 6;
  const int wr = w >> 1, wc = w & 1;
  const int lrow = l & 15, lg = l >> 4;
  const int kq = (lg ^ (lrow & 3)) * 8;          // swizzled read col (halves)
  const int r_a = (w*2)*16 + (l >> 2);           // staging row, first block
  const int r_b = (w*2+1)*16 + (l >> 2);         // staging row, second block
  const int kg = (((l & 3) ^ ((l >> 2) & 3))) * 8;  // swizzled source col

  const _Float16 *srcA0, *srcA1;
  if constexpr (MODE == 1){
    const int bc = blockIdx.y >> 1, xb = (blockIdx.y & 1) * 128;
    int y0i = widx[bc * DLX + xb + r_a];
    int y1i = widx[bc * DLX + xb + r_b];
    srcA0 = A + ((size_t)bc * DLY + y0i) * DD + kg;
    srcA1 = A + ((size_t)bc * DLY + y1i) * DD + kg;
  } else {
    srcA0 = A + (size_t)(rt0 + r_a) * K + kg;
    srcA1 = A + (size_t)(rt0 + r_b) * K + kg;
  }
  const _Float16* srcB0 = B + (size_t)(n0 + r_a) * K + kg;
  const _Float16* srcB1 = B + (size_t)(n0 + r_b) * K + kg;

  f32x4 acc[4][4];
  #pragma unroll
  for (int i = 0; i < 4; i++)
    #pragma unroll
    for (int j = 0; j < 4; j++) acc[i][j] = (f32x4){0.f,0.f,0.f,0.f};

  for (int k0 = 0; k0 < K; k0 += 32){
    __syncthreads();
    gload_lds16(srcA0 + k0, As + (w*2)*512);
    gload_lds16(srcA1 + k0, As + (w*2+1)*512);
    gload_lds16(srcB0 + k0, Bs + (w*2)*512);
    gload_lds16(srcB1 + k0, Bs + (w*2+1)*512);
    __syncthreads();
    f16x8 af[4], bf[4];
    #pragma unroll
    for (int i = 0; i < 4; i++){
      af[i] = *(const f16x8*)&As[(wr*64 + i*16 + lrow)*32 + kq];
      bf[i] = *(const f16x8*)&Bs[(wc*64 + i*16 + lrow)*32 + kq];
    }
    #pragma unroll
    for (int i = 0; i < 4; i++)
      #pragma unroll
      for (int j = 0; j < 4; j++)
        acc[i][j] = __builtin_amdgcn_mfma_f32_16x16x32_f16(af[i], bf[j], acc[i][j], 0, 0, 0);
  }

  if constexpr (MODE == 0){
    #pragma unroll
    for (int mi = 0; mi < 4; mi++)
      #pragma unroll
      for (int ni = 0; ni < 4; ni++){
        int n = n0 + wc*64 + ni*16 + lrow;
        float bv = bias[n];
        #pragma unroll
        for (int r = 0; r < 4; r++){
          int m = wr*64 + mi*16 + lg*4 + r;
          outF[(size_t)(rt0 + m) * DH0 + n] = acc[mi][ni][r] + bv;
        }
      }
  } else if constexpr (MODE == 1){
    const int bc = blockIdx.y >> 1, xb = (blockIdx.y & 1) * 128;
    const int b = bc >> 6;
    #pragma unroll
    for (int mi = 0; mi < 4; mi++)
      #pragma unroll
      for (int ni = 0; ni < 4; ni++){
        int n = n0 + wc*64 + ni*16 + lrow;
        #pragma unroll
        for (int r = 0; r < 4; r++){
          int m = wr*64 + mi*16 + lg*4 + r;
          float x0v = X0[((size_t)b * DLX + xb + m) * DH0 + n];
          float v = softplusf(acc[mi][ni][r] + x0v);
          outH[(size_t)(rt0 + m) * DH0 + n] = (_Float16)v;
        }
      }
  } else {
    float p[4][4];
    #pragma unroll
    for (int mi = 0; mi < 4; mi++)
      #pragma unroll
      for (int r = 0; r < 4; r++) p[mi][r] = 0.f;
    #pragma unroll
    for (int ni = 0; ni < 4; ni++){
      int n = n0 + wc*64 + ni*16 + lrow;
      float b1v = bias[n], w2v = w2[n];
      #pragma unroll
      for (int mi = 0; mi < 4; mi++)
        #pragma unroll
        for (int r = 0; r < 4; r++)
          p[mi][r] += softplusf(acc[mi][ni][r] + b1v) * w2v;
    }
    #pragma unroll
    for (int mi = 0; mi < 4; mi++)
      #pragma unroll
      for (int r = 0; r < 4; r++){
        float s = p[mi][r];
        s += __shfl_xor(s, 1);
        s += __shfl_xor(s, 2);
        s += __shfl_xor(s, 4);
        s += __shfl_xor(s, 8);
        if (lrow == 0){
          size_t t = (size_t)rt0 + wr*64 + mi*16 + lg*4 + r;
          outF[t * 12 + blockIdx.x*2 + wc] = s;
        }
      }
  }
}

// ---------------- final reduce ----------------
__global__ __launch_bounds__(256) void k_reduce(const float* __restrict__ spart,
                                                const float* __restrict__ b2,
                                                float* __restrict__ out){
  int bc = blockIdx.x, tid = threadIdx.x;
  const float* p = spart + ((size_t)bc * DLX + tid) * 12;
  float s = 0.0f;
  #pragma unroll
  for (int j = 0; j < 12; j++) s += p[j];
  __shared__ float red[256];
  red[tid] = s;
  __syncthreads();
  for (int off = 128; off > 0; off >>= 1){
    if (tid < off) red[tid] += red[tid + off];
    __syncthreads();
  }
  if (tid == 0) out[bc] = red[0] + 256.0f * b2[0];
}

extern "C" void kernel_launch(void* const* d_in, const int* in_sizes, int n_in,
                              void* d_out, int out_size, void* d_ws, size_t ws_size,
                              hipStream_t stream){
  const float* xs = (const float*)d_in[0];
  const float* ys = (const float*)d_in[1];
  const float* W0 = (const float*)d_in[2];
  const float* b0 = (const float*)d_in[3];
  const float* W1 = (const float*)d_in[4];
  const float* b1 = (const float*)d_in[5];
  const float* W2 = (const float*)d_in[6];
  const float* b2 = (const float*)d_in[7];
  float* out = (float*)d_out;

  char* wsp = (char*)d_ws;
  size_t off = 0;
  auto alloc = [&](size_t bytes)->void*{
    void* p = wsp + off;
    off += (bytes + 255) & ~(size_t)255;
    return p;
  };
  int* widx        = (int*)alloc((size_t)NTOK * 4);
  _Float16* ys16   = (_Float16*)alloc((size_t)NBC * DLY * DD * 2);   // 201 MB
  _Float16* xs16   = (_Float16*)alloc((size_t)DB * DLX * DD * 2);
  _Float16* W0xf   = (_Float16*)alloc((size_t)DH0 * DD * 2);
  _Float16* W0yf   = (_Float16*)alloc((size_t)DH0 * DD * 2);
  _Float16* W1f    = (_Float16*)alloc((size_t)DH1 * DH0 * 2);
  float* X0        = (float*)alloc((size_t)DB * DLX * DH0 * 4);      // 12.6 MB
  float* spart     = (float*)alloc((size_t)NTOK * 12 * 4);           // 6.3 MB
  _Float16* H0     = (_Float16*)alloc((size_t)NTOK * DH0 * 2);       // 402 MB

  k_cvt16<<<dim3(576),  256, 0, stream>>>(W0, DH0, 0,  DH0, DD, W0xf);
  k_cvt16<<<dim3(576),  256, 0, stream>>>(W0, DH0, DD, DH0, DD, W0yf);
  k_cvt16<<<dim3(576),  256, 0, stream>>>(W1, DH0, 0,  DH1, DH0, W1f);
  k_cvt16<<<dim3(768),  256, 0, stream>>>(xs, DD, 0, DB*DLX, DD, xs16);
  k_cvt16<<<dim3(4096), 256, 0, stream>>>(ys, DD, 0, NBC*DLY, DD, ys16);
  k_scores3<<<dim3(2, NBC), 1024, 0, stream>>>(xs16, ys16, xs, ys, widx);
  k_gemm16<0><<<dim3(12, 16),   256, 0, stream>>>(xs16, W0xf, nullptr, nullptr, b0, nullptr, X0, nullptr);
  k_gemm16<1><<<dim3(12, 1024), 256, 0, stream>>>(ys16, W0yf, widx, X0, nullptr, nullptr, nullptr, H0);
  k_gemm16<2><<<dim3(6, 1024),  256, 0, stream>>>(H0, W1f, nullptr, nullptr, b1, W2, spart, nullptr);
  k_reduce<<<NBC, 256, 0, stream>>>(spart, b2, out);
}

// Round 8
// 1062.690 us; speedup vs baseline: 8.2549x; 1.1198x over previous
//
#include <hip/hip_runtime.h>
#include <stdint.h>

#define DB   8
#define DC   64
#define DLX  256
#define DLY  256
#define DD   768
#define DH0  1536
#define DH1  768
#define NBC  (DB*DC)        // 512
#define NTOK (NBC*DLX)      // 131072
#define TAU  0.25f

typedef float f32x4 __attribute__((ext_vector_type(4)));
typedef _Float16 f16x8 __attribute__((ext_vector_type(8)));
typedef _Float16 f16x4 __attribute__((ext_vector_type(4)));

// fast softplus via hw exp2/log2
__device__ __forceinline__ float softplusf(float x){
  float t = __builtin_amdgcn_exp2f(-fabsf(x) * 1.44269504f);
  return fmaxf(x, 0.0f) + 0.69314718f * __builtin_amdgcn_logf(1.0f + t);
}

// async global->LDS, 16B per lane; lds base wave-uniform (linear dest)
__device__ __forceinline__ void gload_lds16(const void* g, void* l){
  __builtin_amdgcn_global_load_lds((const __attribute__((address_space(1))) void*)g,
                                   (__attribute__((address_space(3))) void*)l,
                                   16, 0, 0);
}

// ---------------- fp32 -> f16 conversion (strided submatrix) ----------------
__global__ __launch_bounds__(256) void k_cvt16(const float* __restrict__ src, int ld, int off,
                                               int rows, int cols, _Float16* __restrict__ dst){
  int total = rows * (cols >> 3);
  for (int idx = blockIdx.x * 256 + threadIdx.x; idx < total; idx += gridDim.x * 256){
    int r = idx / (cols >> 3), c8 = (idx % (cols >> 3)) * 8;
    const float* s = src + (size_t)r * ld + off + c8;
    float4 f0 = *(const float4*)s, f1 = *(const float4*)(s + 4);
    f16x8 v;
    v[0]=(_Float16)f0.x; v[1]=(_Float16)f0.y; v[2]=(_Float16)f0.z; v[3]=(_Float16)f0.w;
    v[4]=(_Float16)f1.x; v[5]=(_Float16)f1.y; v[6]=(_Float16)f1.z; v[7]=(_Float16)f1.w;
    *(f16x8*)(dst + (size_t)r * cols + c8) = v;
  }
}

// ---------------- scores: f16 MFMA + exact fp32 argmax fixup -> widx ----------------
__global__ __launch_bounds__(1024, 1) void k_scores3(const _Float16* __restrict__ xs16,
                                                     const _Float16* __restrict__ ys16,
                                                     const float* __restrict__ xs,
                                                     const float* __restrict__ ys,
                                                     int* __restrict__ widx){
  const int bc = blockIdx.y, b = bc >> 6;
  const int x0 = blockIdx.x * 128;
  const float* X = xs + ((size_t)b * DLX + x0) * DD;
  const float* Y = ys + (size_t)bc * DLY * DD;
  __shared__ __align__(16) _Float16 As[128 * 32];
  __shared__ __align__(16) _Float16 Bs[256 * 32];
  __shared__ float rmx[128][4];
  __shared__ float gm[128];
  __shared__ unsigned short cand[128][8];
  __shared__ int ccnt[128];
  const int tid = threadIdx.x;
  const int l = tid & 63, w = tid >> 6;     // 16 waves
  const int wr = w >> 2, wc = w & 3;        // wave tile 32x64
  const int lrow = l & 15, lg = l >> 4;
  const int kq = (lg ^ (lrow & 3)) * 8;
  const int srow = l >> 2;
  const int kg = (((l & 3) ^ ((l >> 2) & 3))) * 8;
  const _Float16* srcB = ys16 + ((size_t)bc * DLY + w*16 + srow) * DD + kg;
  const _Float16* srcA = xs16 + ((size_t)b * DLX + x0 + (w & 7)*16 + srow) * DD + kg;

  f32x4 acc[2][4];
  #pragma unroll
  for (int i = 0; i < 2; i++)
    #pragma unroll
    for (int j = 0; j < 4; j++) acc[i][j] = (f32x4){0.f,0.f,0.f,0.f};

  for (int k0 = 0; k0 < DD; k0 += 32){
    __syncthreads();
    gload_lds16(srcB + k0, Bs + w*512);
    if (w < 8) gload_lds16(srcA + k0, As + w*512);
    __syncthreads();
    f16x8 af[2], bf[4];
    #pragma unroll
    for (int i = 0; i < 2; i++)
      af[i] = *(const f16x8*)&As[(wr*32 + i*16 + lrow)*32 + kq];
    #pragma unroll
    for (int j = 0; j < 4; j++)
      bf[j] = *(const f16x8*)&Bs[(wc*64 + j*16 + lrow)*32 + kq];
    #pragma unroll
    for (int i = 0; i < 2; i++)
      #pragma unroll
      for (int j = 0; j < 4; j++)
        acc[i][j] = __builtin_amdgcn_mfma_f32_16x16x32_f16(af[i], bf[j], acc[i][j], 0, 0, 0);
  }

  #pragma unroll
  for (int i = 0; i < 2; i++)
    #pragma unroll
    for (int r = 0; r < 4; r++){
      float m = fmaxf(fmaxf(acc[i][0][r], acc[i][1][r]), fmaxf(acc[i][2][r], acc[i][3][r]));
      m = fmaxf(m, __shfl_xor(m, 1));
      m = fmaxf(m, __shfl_xor(m, 2));
      m = fmaxf(m, __shfl_xor(m, 4));
      m = fmaxf(m, __shfl_xor(m, 8));
      if (lrow == 0) rmx[wr*32 + i*16 + lg*4 + r][wc] = m;
    }
  __syncthreads();
  if (tid < 128){
    gm[tid] = fmaxf(fmaxf(rmx[tid][0], rmx[tid][1]), fmaxf(rmx[tid][2], rmx[tid][3]));
    ccnt[tid] = 0;
  }
  __syncthreads();
  #pragma unroll
  for (int i = 0; i < 2; i++)
    #pragma unroll
    for (int r = 0; r < 4; r++){
      int t = wr*32 + i*16 + lg*4 + r;
      float thr = gm[t] - TAU;
      #pragma unroll
      for (int j = 0; j < 4; j++){
        float s = acc[i][j][r];
        if (s >= thr){
          int p = atomicAdd(&ccnt[t], 1);
          if (p < 8) cand[t][p] = (unsigned short)(wc*64 + j*16 + lrow);
        }
      }
    }
  __syncthreads();
  for (int it = 0; it < 8; it++){
    int t = w * 8 + it;
    int cnt = ccnt[t];
    int by;
    if (cnt == 1){
      by = cand[t][0];
    } else {
      const float* xr = X + (size_t)t * DD;
      float best = -1e30f; int besty = 0;
      int n = (cnt <= 8) ? cnt : 256;
      for (int p = 0; p < n; p++){
        int c = (cnt <= 8) ? (int)cand[t][p] : p;
        const float* yr = Y + (size_t)c * DD;
        float s = 0.f;
        #pragma unroll
        for (int q = 0; q < 3; q++){
          float4 xv = *(const float4*)(xr + l*12 + q*4);
          float4 yv = *(const float4*)(yr + l*12 + q*4);
          s += xv.x*yv.x + xv.y*yv.y + xv.z*yv.z + xv.w*yv.w;
        }
        s += __shfl_xor(s, 1);  s += __shfl_xor(s, 2);  s += __shfl_xor(s, 4);
        s += __shfl_xor(s, 8);  s += __shfl_xor(s, 16); s += __shfl_xor(s, 32);
        if (s > best || (s == best && c < besty)){ best = s; besty = c; }
      }
      by = besty;
    }
    if (l == 0) widx[(size_t)bc * DLX + x0 + t] = by;
  }
}

// ---------------- 128x256 f16 MFMA GEMM, 8 waves, XCD-swizzled grid ----------------
// MODE 0: X0h = f16(xs16 @ W0x^T + b0)               (grid 6 x 16)
// MODE 1: H0 = softplus(ys16[widx] @ W0y^T + X0h)    (grid 6 x 1024)
// MODE 2: spart = softplus(H0 @ W1^T + b1) . w2      (grid 3 x 1024)
template<int MODE>
__global__ __launch_bounds__(512) void k_gemm16(const _Float16* __restrict__ A,
        const _Float16* __restrict__ B,
        const int* __restrict__ widx,
        const _Float16* __restrict__ X0h,
        const float* __restrict__ bias,
        const float* __restrict__ w2,
        float* __restrict__ outF,
        _Float16* __restrict__ outH){
  constexpr int K = (MODE == 2) ? DH0 : DD;
  __shared__ __align__(16) _Float16 As[128 * 32];   // 8 KB
  __shared__ __align__(16) _Float16 Bs[256 * 32];   // 16 KB
  const int tid = threadIdx.x;
  // bijective XCD swizzle: consecutive work ids (n-fastest) land on one XCD
  const int gx = gridDim.x, nwg = gx * gridDim.y;
  int lin = blockIdx.x + gx * blockIdx.y;
  int swz = (lin & 7) * (nwg >> 3) + (lin >> 3);
  const int n0  = (swz % gx) * 256;
  const int by  = swz / gx;
  const int rt0 = by * 128;
  const int l = tid & 63, w = tid >> 6;           // 8 waves
  const int wr = w >> 2, wc = w & 3;              // wave tile 64m x 64n
  const int lrow = l & 15, lg = l >> 4;
  const int kq = (lg ^ (lrow & 3)) * 8;           // swizzled read col (halves)
  const int kg = (((l & 3) ^ ((l >> 2) & 3))) * 8; // swizzled source col

  int bc = 0, xb = 0, b = 0;
  if constexpr (MODE == 1){ bc = by >> 1; xb = (by & 1) * 128; b = bc >> 6; }

  // staging: 24 1KB-units (0..7 = A 16-row groups, 8..23 = B), 3 per wave
  const _Float16* gsrc[3];
  _Float16* ldst[3];
  #pragma unroll
  for (int i = 0; i < 3; i++){
    int u = w*3 + i;
    if (u < 8){
      int row = u*16 + (l >> 2);
      if constexpr (MODE == 1){
        int yi = widx[bc * DLX + xb + row];
        gsrc[i] = A + ((size_t)bc * DLY + yi) * DD + kg;
      } else {
        gsrc[i] = A + (size_t)(rt0 + row) * K + kg;
      }
      ldst[i] = (_Float16*)As + u*512;
    } else {
      int row = (u - 8)*16 + (l >> 2);
      gsrc[i] = B + (size_t)(n0 + row) * K + kg;
      ldst[i] = (_Float16*)Bs + (u - 8)*512;
    }
  }

  f32x4 acc[4][4];
  #pragma unroll
  for (int i = 0; i < 4; i++)
    #pragma unroll
    for (int j = 0; j < 4; j++) acc[i][j] = (f32x4){0.f,0.f,0.f,0.f};

  for (int k0 = 0; k0 < K; k0 += 32){
    __syncthreads();
    gload_lds16(gsrc[0] + k0, ldst[0]);
    gload_lds16(gsrc[1] + k0, ldst[1]);
    gload_lds16(gsrc[2] + k0, ldst[2]);
    __syncthreads();
    f16x8 af[4], bf[4];
    #pragma unroll
    for (int i = 0; i < 4; i++){
      af[i] = *(const f16x8*)&As[(wr*64 + i*16 + lrow)*32 + kq];
      bf[i] = *(const f16x8*)&Bs[(wc*64 + i*16 + lrow)*32 + kq];
    }
    #pragma unroll
    for (int i = 0; i < 4; i++)
      #pragma unroll
      for (int j = 0; j < 4; j++)
        acc[i][j] = __builtin_amdgcn_mfma_f32_16x16x32_f16(af[i], bf[j], acc[i][j], 0, 0, 0);
  }

  if constexpr (MODE == 0){
    #pragma unroll
    for (int mi = 0; mi < 4; mi++)
      #pragma unroll
      for (int ni = 0; ni < 4; ni++){
        int n = n0 + wc*64 + ni*16 + lrow;
        float bv = bias[n];
        #pragma unroll
        for (int r = 0; r < 4; r++){
          int m = wr*64 + mi*16 + lg*4 + r;
          outH[(size_t)(rt0 + m) * DH0 + n] = (_Float16)(acc[mi][ni][r] + bv);
        }
      }
  } else if constexpr (MODE == 1){
    #pragma unroll
    for (int mi = 0; mi < 4; mi++)
      #pragma unroll
      for (int ni = 0; ni < 4; ni++){
        int n = n0 + wc*64 + ni*16 + lrow;
        #pragma unroll
        for (int r = 0; r < 4; r++){
          int m = wr*64 + mi*16 + lg*4 + r;
          float x0v = (float)X0h[((size_t)b * DLX + xb + m) * DH0 + n];
          float v = softplusf(acc[mi][ni][r] + x0v);
          outH[(size_t)(rt0 + m) * DH0 + n] = (_Float16)v;
        }
      }
  } else {
    float p[4][4];
    #pragma unroll
    for (int mi = 0; mi < 4; mi++)
      #pragma unroll
      for (int r = 0; r < 4; r++) p[mi][r] = 0.f;
    #pragma unroll
    for (int ni = 0; ni < 4; ni++){
      int n = n0 + wc*64 + ni*16 + lrow;
      float b1v = bias[n], w2v = w2[n];
      #pragma unroll
      for (int mi = 0; mi < 4; mi++)
        #pragma unroll
        for (int r = 0; r < 4; r++)
          p[mi][r] += softplusf(acc[mi][ni][r] + b1v) * w2v;
    }
    const int nb = (int)(swz % gx);
    #pragma unroll
    for (int mi = 0; mi < 4; mi++)
      #pragma unroll
      for (int r = 0; r < 4; r++){
        float s = p[mi][r];
        s += __shfl_xor(s, 1);
        s += __shfl_xor(s, 2);
        s += __shfl_xor(s, 4);
        s += __shfl_xor(s, 8);
        if (lrow == 0){
          size_t t = (size_t)rt0 + wr*64 + mi*16 + lg*4 + r;
          outF[t * 12 + nb*4 + wc] = s;
        }
      }
  }
}

// ---------------- final reduce ----------------
__global__ __launch_bounds__(256) void k_reduce(const float* __restrict__ spart,
                                                const float* __restrict__ b2,
                                                float* __restrict__ out){
  int bc = blockIdx.x, tid = threadIdx.x;
  const float* p = spart + ((size_t)bc * DLX + tid) * 12;
  float s = 0.0f;
  #pragma unroll
  for (int j = 0; j < 12; j++) s += p[j];
  __shared__ float red[256];
  red[tid] = s;
  __syncthreads();
  for (int off = 128; off > 0; off >>= 1){
    if (tid < off) red[tid] += red[tid + off];
    __syncthreads();
  }
  if (tid == 0) out[bc] = red[0] + 256.0f * b2[0];
}

extern "C" void kernel_launch(void* const* d_in, const int* in_sizes, int n_in,
                              void* d_out, int out_size, void* d_ws, size_t ws_size,
                              hipStream_t stream){
  const float* xs = (const float*)d_in[0];
  const float* ys = (const float*)d_in[1];
  const float* W0 = (const float*)d_in[2];
  const float* b0 = (const float*)d_in[3];
  const float* W1 = (const float*)d_in[4];
  const float* b1 = (const float*)d_in[5];
  const float* W2 = (const float*)d_in[6];
  const float* b2 = (const float*)d_in[7];
  float* out = (float*)d_out;

  char* wsp = (char*)d_ws;
  size_t off = 0;
  auto alloc = [&](size_t bytes)->void*{
    void* p = wsp + off;
    off += (bytes + 255) & ~(size_t)255;
    return p;
  };
  int* widx        = (int*)alloc((size_t)NTOK * 4);
  _Float16* ys16   = (_Float16*)alloc((size_t)NBC * DLY * DD * 2);   // 201 MB
  _Float16* xs16   = (_Float16*)alloc((size_t)DB * DLX * DD * 2);
  _Float16* W0xf   = (_Float16*)alloc((size_t)DH0 * DD * 2);
  _Float16* W0yf   = (_Float16*)alloc((size_t)DH0 * DD * 2);
  _Float16* W1f    = (_Float16*)alloc((size_t)DH1 * DH0 * 2);
  _Float16* X0h    = (_Float16*)alloc((size_t)DB * DLX * DH0 * 2);   // 6.3 MB
  float* spart     = (float*)alloc((size_t)NTOK * 12 * 4);           // 6.3 MB
  _Float16* H0     = (_Float16*)alloc((size_t)NTOK * DH0 * 2);       // 402 MB

  k_cvt16<<<dim3(576),  256, 0, stream>>>(W0, DH0, 0,  DH0, DD, W0xf);
  k_cvt16<<<dim3(576),  256, 0, stream>>>(W0, DH0, DD, DH0, DD, W0yf);
  k_cvt16<<<dim3(576),  256, 0, stream>>>(W1, DH0, 0,  DH1, DH0, W1f);
  k_cvt16<<<dim3(768),  256, 0, stream>>>(xs, DD, 0, DB*DLX, DD, xs16);
  k_cvt16<<<dim3(4096), 256, 0, stream>>>(ys, DD, 0, NBC*DLY, DD, ys16);
  k_scores3<<<dim3(2, NBC), 1024, 0, stream>>>(xs16, ys16, xs, ys, widx);
  k_gemm16<0><<<dim3(6, 16),   512, 0, stream>>>(xs16, W0xf, nullptr, nullptr, b0, nullptr, nullptr, X0h);
  k_gemm16<1><<<dim3(6, 1024), 512, 0, stream>>>(ys16, W0yf, widx, X0h, nullptr, nullptr, nullptr, H0);
  k_gemm16<2><<<dim3(3, 1024), 512, 0, stream>>>(H0, W1f, nullptr, nullptr, b1, W2, spart, nullptr);
  k_reduce<<<NBC, 256, 0, stream>>>(spart, b2, out);
}